// Round 12
// baseline (328.789 us; speedup 1.0000x reference)
//
#include <hip/hip_runtime.h>
#include <math.h>

typedef _Float16 f16x8 __attribute__((ext_vector_type(8)));
typedef float f32x4 __attribute__((ext_vector_type(4)));
typedef unsigned short us8 __attribute__((ext_vector_type(8)));

#define PI_F 3.14159265358979323846f

__device__ __forceinline__ void split16(float f, unsigned short& h, unsigned short& l){
  _Float16 hi = (_Float16)f;
  _Float16 lo = (_Float16)(f - (float)hi);
  h = __builtin_bit_cast(unsigned short, hi);
  l = __builtin_bit_cast(unsigned short, lo);
}

__device__ __forceinline__ float fast_gelu(float v){
  float u2 = v * v;
  float z  = v * fmaf(u2, 0.03567740814f, 0.7978845608f);
  float e  = __builtin_amdgcn_exp2f(z * 2.885390082f);   // 2*log2(e)
  float r  = __builtin_amdgcn_rcpf(e + 1.0f);
  return v - v * r;
}

__device__ __forceinline__ float fast_tanh(float v){
  float e = __builtin_amdgcn_exp2f(v * 2.885390082f);
  float r = __builtin_amdgcn_rcpf(e + 1.0f);
  return 1.0f - 2.0f * r;
}

// LDS tile addressing in ushort units, XOR swizzle for bank balance
#define ACOL(rr,cc) (((rr) << 8) + ((cc) ^ ((((rr) & 15)) << 3)))

#define LDW(ptr) __builtin_bit_cast(f16x8, *reinterpret_cast<const us8*>(ptr))

// ---------------- pyramid (jax.image.resize bilinear, antialias=True) -------
__global__ void pyr_kernel(const float* __restrict__ fg, float* __restrict__ out,
                           int Ho, int Wo, float inv_scale){
  int idx = blockIdx.x * blockDim.x + threadIdx.x;
  int total = 8 * Ho * Wo * 64;
  if (idx >= total) return;
  int c  = idx & 63;
  int xy = idx >> 6;
  int x  = xy % Wo;
  int y  = (xy / Wo) % Ho;
  int b  = xy / (Wo * Ho);
  float cyc = inv_scale * (y + 0.5f) - 0.5f;
  float cxc = inv_scale * (x + 0.5f) - 0.5f;
  int iy0 = (int)ceilf(cyc - inv_scale); if (iy0 < 0) iy0 = 0;
  int iy1 = (int)floorf(cyc + inv_scale); if (iy1 > 63) iy1 = 63;
  int ix0 = (int)ceilf(cxc - inv_scale); if (ix0 < 0) ix0 = 0;
  int ix1 = (int)floorf(cxc + inv_scale); if (ix1 > 63) ix1 = 63;
  float rinv = 1.0f / inv_scale;
  float wxs = 0.0f;
  for (int ix = ix0; ix <= ix1; ++ix){
    float w = 1.0f - fabsf(ix - cxc) * rinv;
    if (w > 0.0f) wxs += w;
  }
  float wys = 0.0f, acc = 0.0f;
  for (int iy = iy0; iy <= iy1; ++iy){
    float wy = 1.0f - fabsf(iy - cyc) * rinv;
    if (wy <= 0.0f) continue;
    wys += wy;
    const float* rowp = fg + (((b * 64) + iy) * 64) * 64 + c;
    for (int ix = ix0; ix <= ix1; ++ix){
      float wx = 1.0f - fabsf(ix - cxc) * rinv;
      if (wx <= 0.0f) continue;
      acc += wy * wx * rowp[ix * 64];
    }
  }
  out[idx] = acc / (wys * wxs);
}

// ------------- weight prep: pre-tiled per-lane MFMA fragments ---------------
// WT[l][cfg][ks][lane][e]: col = cfg*16 + (lane&15), k = ks*32 + (lane>>4)*8 + e
// layer0 k-remap: k<42 -> W0 row k; 42..47 pad; 48..239 -> row k-6; 240..255 pad
__global__ void prep_wt(const float* __restrict__ W0, const float* __restrict__ W1,
                        const float* __restrict__ W2, const float* __restrict__ W3,
                        unsigned short* __restrict__ WTh, unsigned short* __restrict__ WTl){
  int idx = blockIdx.x * 256 + threadIdx.x;      // < 262144
  int l    = idx >> 16;
  int cfg  = (idx >> 12) & 15;
  int ks   = (idx >> 9) & 7;
  int lane = (idx >> 3) & 63;
  int e    = idx & 7;
  int col  = cfg * 16 + (lane & 15);
  int k    = ks * 32 + (lane >> 4) * 8 + e;
  float v;
  if (l == 0){
    int row; bool valid;
    if (k < 42)                 { row = k;     valid = true; }
    else if (k >= 48 && k < 240){ row = k - 6; valid = true; }
    else                        { row = 0;     valid = false; }
    v = valid ? W0[row * 256 + col] : 0.0f;
  } else {
    const float* W = (l == 1) ? W1 : ((l == 2) ? W2 : W3);
    v = W[k * 256 + col];
  }
  unsigned short h, lo;
  split16(v, h, lo);
  WTh[idx] = h;
  WTl[idx] = lo;
}

// ------------- FiLM params + Wout tiled fragments ----------------------------
__global__ void prep_misc(const float* __restrict__ cv, const float* __restrict__ Wc,
                          const float* __restrict__ bc, const float* __restrict__ Wout,
                          float* __restrict__ gamma, float* __restrict__ beta,
                          unsigned short* __restrict__ WoT){
  int idx = blockIdx.x * 256 + threadIdx.x;      // < 8192
  if (idx < 4096){
    int b = idx >> 9, j = idx & 511;
    float a = bc[j];
    for (int c = 0; c < 64; ++c) a += cv[b * 64 + c] * Wc[c * 512 + j];
    if (j < 256) gamma[b * 256 + j] = a + 1.0f;
    else         beta[b * 256 + (j - 256)] = a;
  } else {
    int j = idx - 4096;                // WoT[ks][lane][e]
    int ks = j >> 9, lane = (j >> 3) & 63, e = j & 7;
    int col = lane & 15;
    int k = ks * 32 + (lane >> 4) * 8 + e;
    float v = (col < 3) ? Wout[k * 3 + col] : 0.0f;
    _Float16 h = (_Float16)v;
    WoT[j] = __builtin_bit_cast(unsigned short, h);
  }
}

// --------- R10-verbatim K-loop over one 64-row tile (ping-pong B) -----------
__device__ __forceinline__ void kloop_tile(const unsigned short* __restrict__ AH,
                                           const unsigned short* __restrict__ AL,
                                           const unsigned short* __restrict__ Wh,
                                           const unsigned short* __restrict__ Wl_,
                                           int bbase, int l15, int lg,
                                           f32x4 (&acc)[4][2]){
#pragma unroll
  for (int rf = 0; rf < 4; ++rf)
#pragma unroll
    for (int cf = 0; cf < 2; ++cf)
      acc[rf][cf] = (f32x4){0.0f, 0.0f, 0.0f, 0.0f};

  f16x8 bh[2][2], bl[2][2];
#pragma unroll
  for (int cf = 0; cf < 2; ++cf){
    bh[0][cf] = LDW(Wh  + bbase + cf * 4096);
    bl[0][cf] = LDW(Wl_ + bbase + cf * 4096);
  }

#pragma unroll
  for (int ks = 0; ks < 8; ++ks){
    const int cur = ks & 1, nxt = cur ^ 1;
    if (ks < 7){
#pragma unroll
      for (int cf = 0; cf < 2; ++cf){
        bh[nxt][cf] = LDW(Wh  + bbase + cf * 4096 + (ks + 1) * 512);
        bl[nxt][cf] = LDW(Wl_ + bbase + cf * 4096 + (ks + 1) * 512);
      }
    }
    const int kc = ks * 32 + lg * 8;
    f16x8 ah[4], alv[4];
#pragma unroll
    for (int rf = 0; rf < 4; ++rf){
      ah[rf]  = LDW(&AH[ACOL(rf * 16 + l15, kc)]);
      alv[rf] = LDW(&AL[ACOL(rf * 16 + l15, kc)]);
    }
#pragma unroll
    for (int cf = 0; cf < 2; ++cf){
#pragma unroll
      for (int rf = 0; rf < 4; ++rf){
        acc[rf][cf] = __builtin_amdgcn_mfma_f32_16x16x32_f16(ah[rf],  bh[cur][cf], acc[rf][cf], 0, 0, 0);
        acc[rf][cf] = __builtin_amdgcn_mfma_f32_16x16x32_f16(alv[rf], bh[cur][cf], acc[rf][cf], 0, 0, 0);
        acc[rf][cf] = __builtin_amdgcn_mfma_f32_16x16x32_f16(ah[rf],  bl[cur][cf], acc[rf][cf], 0, 0, 0);
      }
    }
  }
}

// --------- R10-verbatim FiLM+gelu epilogue over one tile --------------------
__device__ __forceinline__ void epi_tile(unsigned short* __restrict__ AH,
                                         unsigned short* __restrict__ AL,
                                         const f32x4 (&acc)[4][2],
                                         const float (&gmv)[2], const float (&btv)[2],
                                         const float (&bsl)[2],
                                         int cb, int l15, int lg){
#pragma unroll
  for (int rf = 0; rf < 4; ++rf){
#pragma unroll
    for (int cf = 0; cf < 2; ++cf){
      const int col = cb + cf * 16 + l15;
      const float gm = gmv[cf], bt = btv[cf], bs = bsl[cf];
#pragma unroll
      for (int rg = 0; rg < 4; ++rg){
        const int row = rf * 16 + lg * 4 + rg;   // measured C/D layout (m89)
        float v = fmaf(acc[rf][cf][rg] + bs, gm, bt);
        float gg = fast_gelu(v);
        unsigned short h, lo;
        split16(gg, h, lo);
        AH[ACOL(row, col)] = h;
        AL[ACOL(row, col)] = lo;
      }
    }
  }
}

// ------------------------------- main ---------------------------------------
// R10 config (512thr, 8 waves/CU — the proven-safe residency) with a two-tile
// software pipeline: 128 rows/block in two disjoint 64-row LDS tile pairs
// (4x32KB = 128KB, 1 block/CU). Per layer: K(T0); bar; EPI(T0)+K(T1); bar;
// EPI(T1) — halves barrier count per row and mixes VALU epilogue with the
// other tile's MFMA stream so the matrix pipe stays fed. Phase 0 and head now
// use all 512 threads.
__global__ __launch_bounds__(512, 2)
void dec_main(const float* __restrict__ fg, const float* __restrict__ coords,
              const float* __restrict__ p1, const float* __restrict__ p2,
              const unsigned short* __restrict__ WTh, const unsigned short* __restrict__ WTl,
              const unsigned short* __restrict__ WoT,
              const float* __restrict__ gamma, const float* __restrict__ beta,
              const float* __restrict__ b0, const float* __restrict__ b1,
              const float* __restrict__ b2, const float* __restrict__ b3,
              const float* __restrict__ bout, float* __restrict__ out){
  __shared__ __align__(16) unsigned short Ah0[64 * 256];  // 32 KB
  __shared__ __align__(16) unsigned short Al0[64 * 256];  // 32 KB
  __shared__ __align__(16) unsigned short Ah1[64 * 256];  // 32 KB
  __shared__ __align__(16) unsigned short Al1[64 * 256];  // 32 KB

  const int t  = threadIdx.x;
  const int bi = blockIdx.x >> 7;           // image 0..7 (1024 blocks, 128 rows each)
  const int n0 = (blockIdx.x & 127) * 128;  // first coord row of this block

  const int lane = t & 63;
  const int wv   = t >> 6;         // 0..7
  const int cb   = wv * 32;        // this wave's 32-col slice (both tiles)
  const int l15  = lane & 15;
  const int lg   = lane >> 4;

  // FiLM params + biases for this lane's 2 columns (registers, R10-validated;
  // same bi for both tiles so shared across the pipeline)
  float gmv[2], btv[2], bsv[4][2];
#pragma unroll
  for (int cf = 0; cf < 2; ++cf){
    const int col = cb + cf * 16 + l15;
    gmv[cf] = gamma[bi * 256 + col];
    btv[cf] = beta[bi * 256 + col];
    bsv[0][cf] = b0[col]; bsv[1][cf] = b1[col];
    bsv[2][cf] = b2[col]; bsv[3][cf] = b3[col];
  }

  // ---------------- phase 0: build features (split f16, swizzled) ----------
  // R4-validated body; all 512 threads, 4 threads/row over 2 tiles x 64 rows
  {
    const int tile = t >> 8;
    const int r = (t >> 2) & 63, q = t & 3;
    const int n = n0 + tile * 64 + r;
    unsigned short* AhP = tile ? Ah1 : Ah0;
    unsigned short* AlP = tile ? Al1 : Al0;
    const float cy = coords[2 * n], cx = coords[2 * n + 1];

    if (q == 0){
      float e[48];
      e[0] = cy; e[1] = cx;
#pragma unroll
      for (int i = 0; i < 10; ++i){
        float f = PI_F * (float)(1 << i);
        float sy, cyv, sx, cxv;
        sincosf(cy * f, &sy, &cyv);
        sincosf(cx * f, &sx, &cxv);
        e[2 + 4 * i] = sy;
        e[3 + 4 * i] = sx;
        e[4 + 4 * i] = cyv;
        e[5 + 4 * i] = cxv;
      }
#pragma unroll
      for (int j = 42; j < 48; ++j) e[j] = 0.0f;
#pragma unroll
      for (int u = 0; u < 6; ++u){
        us8 vh, vl;
#pragma unroll
        for (int j = 0; j < 8; ++j){
          unsigned short h, l;
          split16(e[8 * u + j], h, l);
          vh[j] = h; vl[j] = l;
        }
        *reinterpret_cast<us8*>(&AhP[ACOL(r, u * 8)]) = vh;
        *reinterpret_cast<us8*>(&AlP[ACOL(r, u * 8)]) = vl;
      }
    }
    if (q == 1){   // zero pad cols 240..255
      us8 z = {0,0,0,0,0,0,0,0};
      *reinterpret_cast<us8*>(&AhP[ACOL(r, 240)]) = z;
      *reinterpret_cast<us8*>(&AhP[ACOL(r, 248)]) = z;
      *reinterpret_cast<us8*>(&AlP[ACOL(r, 240)]) = z;
      *reinterpret_cast<us8*>(&AlP[ACOL(r, 248)]) = z;
    }

    // bilinear sample 16 channels per thread from each pyramid level
#pragma unroll
    for (int L = 0; L < 3; ++L){
      const int HL = 64 >> L;
      const float* g = (L == 0) ? fg : ((L == 1) ? p1 : p2);
      float yy = (cy + 1.0f) * 0.5f * (HL - 1);
      float xx = (cx + 1.0f) * 0.5f * (HL - 1);
      float y0f = floorf(yy), x0f = floorf(xx);
      float wy = yy - y0f, wx = xx - x0f;
      int y0 = (int)y0f, x0 = (int)x0f;
      y0 = min(max(y0, 0), HL - 1); x0 = min(max(x0, 0), HL - 1);
      int y1 = min(y0 + 1, HL - 1), x1 = min(x0 + 1, HL - 1);
      const int c0 = q * 16;
      const float* g00 = g + (((bi * HL + y0) * HL) + x0) * 64 + c0;
      const float* g01 = g + (((bi * HL + y0) * HL) + x1) * 64 + c0;
      const float* g10 = g + (((bi * HL + y1) * HL) + x0) * 64 + c0;
      const float* g11 = g + (((bi * HL + y1) * HL) + x1) * 64 + c0;
      float w00 = (1 - wy) * (1 - wx), w01 = (1 - wy) * wx;
      float w10 = wy * (1 - wx),       w11 = wy * wx;
      float o[16];
#pragma unroll
      for (int u = 0; u < 4; ++u){
        float4 v0 = *reinterpret_cast<const float4*>(g00 + 4 * u);
        float4 v1 = *reinterpret_cast<const float4*>(g01 + 4 * u);
        float4 v2 = *reinterpret_cast<const float4*>(g10 + 4 * u);
        float4 v3 = *reinterpret_cast<const float4*>(g11 + 4 * u);
        o[4*u+0] = w00*v0.x + w01*v1.x + w10*v2.x + w11*v3.x;
        o[4*u+1] = w00*v0.y + w01*v1.y + w10*v2.y + w11*v3.y;
        o[4*u+2] = w00*v0.z + w01*v1.z + w10*v2.z + w11*v3.z;
        o[4*u+3] = w00*v0.w + w01*v1.w + w10*v2.w + w11*v3.w;
      }
      us8 h0, h1, l0, l1;
#pragma unroll
      for (int j = 0; j < 8; ++j){
        unsigned short h, l;
        split16(o[j], h, l);      h0[j] = h; l0[j] = l;
        split16(o[8 + j], h, l);  h1[j] = h; l1[j] = l;
      }
      const int colb = 48 + 64 * L + 16 * q;
      *reinterpret_cast<us8*>(&AhP[ACOL(r, colb)])     = h0;
      *reinterpret_cast<us8*>(&AhP[ACOL(r, colb + 8)]) = h1;
      *reinterpret_cast<us8*>(&AlP[ACOL(r, colb)])     = l0;
      *reinterpret_cast<us8*>(&AlP[ACOL(r, colb + 8)]) = l1;
    }
  }
  __syncthreads();

  // ---------------- phase 1: 4 layers, two-tile pipeline -------------------
  const int bbase = wv * 8192 + lane * 8;   // cfg = wv*2+cf

  for (int l = 0; l < 4; ++l){
    const unsigned short* Wh  = WTh + l * 65536;
    const unsigned short* Wl_ = WTl + l * 65536;
    f32x4 acc[4][2];

    kloop_tile(Ah0, Al0, Wh, Wl_, bbase, l15, lg, acc);   // reads T0
    __syncthreads();                                       // (a)
    epi_tile(Ah0, Al0, acc, gmv, btv, bsv[l], cb, l15, lg);// writes T0
    kloop_tile(Ah1, Al1, Wh, Wl_, bbase, l15, lg, acc);   // reads T1 (disjoint)
    __syncthreads();                                       // (b)
    epi_tile(Ah1, Al1, acc, gmv, btv, bsv[l], cb, l15, lg);// writes T1
  }
  __syncthreads();   // T1 epilogue visible before head reads

  // ---------------- phase 2: output head (256 -> 3) + tanh, all 8 waves ----
  {
    const int tile = wv >> 2, sub = wv & 3;
    const unsigned short* AhP = tile ? Ah1 : Ah0;
    const unsigned short* AlP = tile ? Al1 : Al0;
    f32x4 ao = (f32x4){0.0f, 0.0f, 0.0f, 0.0f};
#pragma unroll
    for (int ks = 0; ks < 8; ++ks){
      const int kc = ks * 32 + lg * 8;
      f16x8 va = LDW(&AhP[ACOL(sub * 16 + l15, kc)]);
      f16x8 vl = LDW(&AlP[ACOL(sub * 16 + l15, kc)]);
      f16x8 vb = LDW(&WoT[(ks * 64 + lane) * 8]);
      ao = __builtin_amdgcn_mfma_f32_16x16x32_f16(va, vb, ao, 0, 0, 0);
      ao = __builtin_amdgcn_mfma_f32_16x16x32_f16(vl, vb, ao, 0, 0, 0);
    }
    if (l15 < 3){
      const float bo = bout[l15];
#pragma unroll
      for (int rg = 0; rg < 4; ++rg){
        const int row = tile * 64 + sub * 16 + lg * 4 + rg;
        out[((size_t)bi * 16384 + n0 + row) * 3 + l15] = fast_tanh(ao[rg] + bo);
      }
    }
  }
}

// ------------------------------- launch --------------------------------------
extern "C" void kernel_launch(void* const* d_in, const int* in_sizes, int n_in,
                              void* d_out, int out_size, void* d_ws, size_t ws_size,
                              hipStream_t stream){
  (void)in_sizes; (void)n_in; (void)out_size; (void)ws_size;
  const float* fg     = (const float*)d_in[0];
  const float* cv     = (const float*)d_in[1];
  const float* coords = (const float*)d_in[2];
  const float* Wc     = (const float*)d_in[3];
  const float* bc     = (const float*)d_in[4];
  const float* W0     = (const float*)d_in[5];
  const float* b0     = (const float*)d_in[6];
  const float* W1     = (const float*)d_in[7];
  const float* b1     = (const float*)d_in[8];
  const float* W2     = (const float*)d_in[9];
  const float* b2     = (const float*)d_in[10];
  const float* W3     = (const float*)d_in[11];
  const float* b3     = (const float*)d_in[12];
  const float* Wout   = (const float*)d_in[13];
  const float* bout   = (const float*)d_in[14];

  char* ws = (char*)d_ws;
  float*          p1    = (float*)(ws);                    // 8*32*32*64 f32 = 2 MB
  float*          p2    = (float*)(ws + 2097152);          // 8*16*16*64 f32 = 512 KB
  unsigned short* WTh   = (unsigned short*)(ws + 2621440); // 4*256*256 f16 = 512 KB
  unsigned short* WTl   = (unsigned short*)(ws + 3145728); // 512 KB
  unsigned short* WoT   = (unsigned short*)(ws + 3670016); // 8*64*8 f16
  float*          gam   = (float*)(ws + 3678208);          // 8*256 f32
  float*          bet   = (float*)(ws + 3686400);          // 8*256 f32
  float*          outp  = (float*)d_out;

  pyr_kernel<<<dim3(2048), dim3(256), 0, stream>>>(fg, p1, 32, 32, 2.0f);
  pyr_kernel<<<dim3(512),  dim3(256), 0, stream>>>(fg, p2, 16, 16, 4.0f);
  prep_wt  <<<dim3(1024),  dim3(256), 0, stream>>>(W0, W1, W2, W3, WTh, WTl);
  prep_misc<<<dim3(32),    dim3(256), 0, stream>>>(cv, Wc, bc, Wout, gam, bet, WoT);
  dec_main <<<dim3(1024),  dim3(512), 0, stream>>>(fg, coords, p1, p2, WTh, WTl, WoT,
                                                   gam, bet, b0, b1, b2, b3, bout, outp);
}

// Round 13
// 320.804 us; speedup vs baseline: 1.0249x; 1.0249x over previous
//
#include <hip/hip_runtime.h>
#include <math.h>

typedef _Float16 f16x8 __attribute__((ext_vector_type(8)));
typedef float f32x4 __attribute__((ext_vector_type(4)));
typedef float f32x16 __attribute__((ext_vector_type(16)));
typedef unsigned short us8 __attribute__((ext_vector_type(8)));

#define PI_F 3.14159265358979323846f

__device__ __forceinline__ void split16(float f, unsigned short& h, unsigned short& l){
  _Float16 hi = (_Float16)f;
  _Float16 lo = (_Float16)(f - (float)hi);
  h = __builtin_bit_cast(unsigned short, hi);
  l = __builtin_bit_cast(unsigned short, lo);
}

__device__ __forceinline__ float fast_gelu(float v){
  float u2 = v * v;
  float z  = v * fmaf(u2, 0.03567740814f, 0.7978845608f);
  float e  = __builtin_amdgcn_exp2f(z * 2.885390082f);   // 2*log2(e)
  float r  = __builtin_amdgcn_rcpf(e + 1.0f);
  return v - v * r;
}

__device__ __forceinline__ float fast_tanh(float v){
  float e = __builtin_amdgcn_exp2f(v * 2.885390082f);
  float r = __builtin_amdgcn_rcpf(e + 1.0f);
  return 1.0f - 2.0f * r;
}

// LDS tile addressing in ushort units, XOR swizzle for bank balance
#define ACOL(rr,cc) (((rr) << 8) + ((cc) ^ ((((rr) & 15)) << 3)))

#define LDW(ptr) __builtin_bit_cast(f16x8, *reinterpret_cast<const us8*>(ptr))

// ---------------- pyramid (jax.image.resize bilinear, antialias=True) -------
__global__ void pyr_kernel(const float* __restrict__ fg, float* __restrict__ out,
                           int Ho, int Wo, float inv_scale){
  int idx = blockIdx.x * blockDim.x + threadIdx.x;
  int total = 8 * Ho * Wo * 64;
  if (idx >= total) return;
  int c  = idx & 63;
  int xy = idx >> 6;
  int x  = xy % Wo;
  int y  = (xy / Wo) % Ho;
  int b  = xy / (Wo * Ho);
  float cyc = inv_scale * (y + 0.5f) - 0.5f;
  float cxc = inv_scale * (x + 0.5f) - 0.5f;
  int iy0 = (int)ceilf(cyc - inv_scale); if (iy0 < 0) iy0 = 0;
  int iy1 = (int)floorf(cyc + inv_scale); if (iy1 > 63) iy1 = 63;
  int ix0 = (int)ceilf(cxc - inv_scale); if (ix0 < 0) ix0 = 0;
  int ix1 = (int)floorf(cxc + inv_scale); if (ix1 > 63) ix1 = 63;
  float rinv = 1.0f / inv_scale;
  float wxs = 0.0f;
  for (int ix = ix0; ix <= ix1; ++ix){
    float w = 1.0f - fabsf(ix - cxc) * rinv;
    if (w > 0.0f) wxs += w;
  }
  float wys = 0.0f, acc = 0.0f;
  for (int iy = iy0; iy <= iy1; ++iy){
    float wy = 1.0f - fabsf(iy - cyc) * rinv;
    if (wy <= 0.0f) continue;
    wys += wy;
    const float* rowp = fg + (((b * 64) + iy) * 64) * 64 + c;
    for (int ix = ix0; ix <= ix1; ++ix){
      float wx = 1.0f - fabsf(ix - cxc) * rinv;
      if (wx <= 0.0f) continue;
      acc += wy * wx * rowp[ix * 64];
    }
  }
  out[idx] = acc / (wys * wxs);
}

// ------------- weight prep: pre-tiled per-lane 32x32x16 MFMA fragments ------
// WT[l][cfg][ks][lane][e]: col = cfg*32 + (lane&31), k = ks*16 + (lane>>5)*8 + e
// (cfg in [0,8), ks in [0,16)) — same slot-consistent map used for A fragments.
// layer0 k-remap: k<42 -> W0 row k; 42..47 pad; 48..239 -> row k-6; 240..255 pad
__global__ void prep_wt(const float* __restrict__ W0, const float* __restrict__ W1,
                        const float* __restrict__ W2, const float* __restrict__ W3,
                        unsigned short* __restrict__ WTh, unsigned short* __restrict__ WTl){
  int idx = blockIdx.x * 256 + threadIdx.x;      // < 262144
  int l    = idx >> 16;
  int rem  = idx & 65535;
  int cfg  = rem >> 13;          // 0..7
  int ks   = (rem >> 9) & 15;    // 0..15
  int lane = (rem >> 3) & 63;
  int e    = idx & 7;
  int col  = cfg * 32 + (lane & 31);
  int k    = ks * 16 + (lane >> 5) * 8 + e;
  float v;
  if (l == 0){
    int row; bool valid;
    if (k < 42)                 { row = k;     valid = true; }
    else if (k >= 48 && k < 240){ row = k - 6; valid = true; }
    else                        { row = 0;     valid = false; }
    v = valid ? W0[row * 256 + col] : 0.0f;
  } else {
    const float* W = (l == 1) ? W1 : ((l == 2) ? W2 : W3);
    v = W[k * 256 + col];
  }
  unsigned short h, lo;
  split16(v, h, lo);
  WTh[idx] = h;
  WTl[idx] = lo;
}

// ------------- FiLM params + Wout tiled fragments (16x16 head, unchanged) ---
__global__ void prep_misc(const float* __restrict__ cv, const float* __restrict__ Wc,
                          const float* __restrict__ bc, const float* __restrict__ Wout,
                          float* __restrict__ gamma, float* __restrict__ beta,
                          unsigned short* __restrict__ WoT){
  int idx = blockIdx.x * 256 + threadIdx.x;      // < 8192
  if (idx < 4096){
    int b = idx >> 9, j = idx & 511;
    float a = bc[j];
    for (int c = 0; c < 64; ++c) a += cv[b * 64 + c] * Wc[c * 512 + j];
    if (j < 256) gamma[b * 256 + j] = a + 1.0f;
    else         beta[b * 256 + (j - 256)] = a;
  } else {
    int j = idx - 4096;                // WoT[ks][lane][e]
    int ks = j >> 9, lane = (j >> 3) & 63, e = j & 7;
    int col = lane & 15;
    int k = ks * 32 + (lane >> 4) * 8 + e;
    float v = (col < 3) ? Wout[k * 3 + col] : 0.0f;
    _Float16 h = (_Float16)v;
    WoT[j] = __builtin_bit_cast(unsigned short, h);
  }
}

// ------------------------------- main ---------------------------------------
// R10 config (512thr, (512,2), 64-row tile, 1 block/CU) with the layer GEMMs
// on 32x32x16 MFMA: half the MFMA instructions at the higher 32x32 pipe rate.
// C/D layout per measured m74/m101: col=lane&31, row=(reg&3)+8*(reg>>2)+4*(lane>>5).
__global__ __launch_bounds__(512, 2)
void dec_main(const float* __restrict__ fg, const float* __restrict__ coords,
              const float* __restrict__ p1, const float* __restrict__ p2,
              const unsigned short* __restrict__ WTh, const unsigned short* __restrict__ WTl,
              const unsigned short* __restrict__ WoT,
              const float* __restrict__ gamma, const float* __restrict__ beta,
              const float* __restrict__ b0, const float* __restrict__ b1,
              const float* __restrict__ b2, const float* __restrict__ b3,
              const float* __restrict__ bout, float* __restrict__ out){
  __shared__ __align__(16) unsigned short Ah[64 * 256];  // 32 KB hi tile
  __shared__ __align__(16) unsigned short Al[64 * 256];  // 32 KB lo tile

  const int t  = threadIdx.x;
  const int bi = blockIdx.x >> 8;           // image 0..7   (R4-validated decode)
  const int n0 = (blockIdx.x & 255) * 64;   // first coord row of this block

  const int lane = t & 63;
  const int wv   = t >> 6;         // 0..7
  const int l15  = lane & 15;      // head (16x16) lane decode
  const int lg   = lane >> 4;
  const int l31  = lane & 31;      // 32x32 lane decode
  const int lhi  = lane >> 5;      // 0/1

  // FiLM params + biases: single column per lane (col = wv*32 + l31)
  const int mycol = wv * 32 + l31;
  const float gmv = gamma[bi * 256 + mycol];
  const float btv = beta[bi * 256 + mycol];
  float bsv[4];
  bsv[0] = b0[mycol]; bsv[1] = b1[mycol];
  bsv[2] = b2[mycol]; bsv[3] = b3[mycol];

  // ---------------- phase 0: build features (split f16, swizzled) ----------
  // R4-validated body verbatim, gated to t<256 (4 threads/row over 64 rows)
  if (t < 256){
    const int r = t >> 2, q = t & 3;
    const int n = n0 + r;
    const float cy = coords[2 * n], cx = coords[2 * n + 1];

    if (q == 0){
      float e[48];
      e[0] = cy; e[1] = cx;
#pragma unroll
      for (int i = 0; i < 10; ++i){
        float f = PI_F * (float)(1 << i);
        float sy, cyv, sx, cxv;
        sincosf(cy * f, &sy, &cyv);
        sincosf(cx * f, &sx, &cxv);
        e[2 + 4 * i] = sy;
        e[3 + 4 * i] = sx;
        e[4 + 4 * i] = cyv;
        e[5 + 4 * i] = cxv;
      }
#pragma unroll
      for (int j = 42; j < 48; ++j) e[j] = 0.0f;
#pragma unroll
      for (int u = 0; u < 6; ++u){
        us8 vh, vl;
#pragma unroll
        for (int j = 0; j < 8; ++j){
          unsigned short h, l;
          split16(e[8 * u + j], h, l);
          vh[j] = h; vl[j] = l;
        }
        *reinterpret_cast<us8*>(&Ah[ACOL(r, u * 8)]) = vh;
        *reinterpret_cast<us8*>(&Al[ACOL(r, u * 8)]) = vl;
      }
    }
    if (q == 1){   // zero pad cols 240..255
      us8 z = {0,0,0,0,0,0,0,0};
      *reinterpret_cast<us8*>(&Ah[ACOL(r, 240)]) = z;
      *reinterpret_cast<us8*>(&Ah[ACOL(r, 248)]) = z;
      *reinterpret_cast<us8*>(&Al[ACOL(r, 240)]) = z;
      *reinterpret_cast<us8*>(&Al[ACOL(r, 248)]) = z;
    }

    // bilinear sample 16 channels per thread from each pyramid level
#pragma unroll
    for (int L = 0; L < 3; ++L){
      const int HL = 64 >> L;
      const float* g = (L == 0) ? fg : ((L == 1) ? p1 : p2);
      float yy = (cy + 1.0f) * 0.5f * (HL - 1);
      float xx = (cx + 1.0f) * 0.5f * (HL - 1);
      float y0f = floorf(yy), x0f = floorf(xx);
      float wy = yy - y0f, wx = xx - x0f;
      int y0 = (int)y0f, x0 = (int)x0f;
      y0 = min(max(y0, 0), HL - 1); x0 = min(max(x0, 0), HL - 1);
      int y1 = min(y0 + 1, HL - 1), x1 = min(x0 + 1, HL - 1);
      const int c0 = q * 16;
      const float* g00 = g + (((bi * HL + y0) * HL) + x0) * 64 + c0;
      const float* g01 = g + (((bi * HL + y0) * HL) + x1) * 64 + c0;
      const float* g10 = g + (((bi * HL + y1) * HL) + x0) * 64 + c0;
      const float* g11 = g + (((bi * HL + y1) * HL) + x1) * 64 + c0;
      float w00 = (1 - wy) * (1 - wx), w01 = (1 - wy) * wx;
      float w10 = wy * (1 - wx),       w11 = wy * wx;
      float o[16];
#pragma unroll
      for (int u = 0; u < 4; ++u){
        float4 v0 = *reinterpret_cast<const float4*>(g00 + 4 * u);
        float4 v1 = *reinterpret_cast<const float4*>(g01 + 4 * u);
        float4 v2 = *reinterpret_cast<const float4*>(g10 + 4 * u);
        float4 v3 = *reinterpret_cast<const float4*>(g11 + 4 * u);
        o[4*u+0] = w00*v0.x + w01*v1.x + w10*v2.x + w11*v3.x;
        o[4*u+1] = w00*v0.y + w01*v1.y + w10*v2.y + w11*v3.y;
        o[4*u+2] = w00*v0.z + w01*v1.z + w10*v2.z + w11*v3.z;
        o[4*u+3] = w00*v0.w + w01*v1.w + w10*v2.w + w11*v3.w;
      }
      us8 h0, h1, l0, l1;
#pragma unroll
      for (int j = 0; j < 8; ++j){
        unsigned short h, l;
        split16(o[j], h, l);      h0[j] = h; l0[j] = l;
        split16(o[8 + j], h, l);  h1[j] = h; l1[j] = l;
      }
      const int colb = 48 + 64 * L + 16 * q;
      *reinterpret_cast<us8*>(&Ah[ACOL(r, colb)])     = h0;
      *reinterpret_cast<us8*>(&Ah[ACOL(r, colb + 8)]) = h1;
      *reinterpret_cast<us8*>(&Al[ACOL(r, colb)])     = l0;
      *reinterpret_cast<us8*>(&Al[ACOL(r, colb + 8)]) = l1;
    }
  }
  __syncthreads();

  // ---------------- phase 1: 4 FiLM-gelu MLP layers (32x32x16, split f16) --
  // B fragments pre-tiled: offset = cfg*8192 + ks*512 + lane*8, cfg = wv
  const int bbase = wv * 8192 + lane * 8;

  for (int l = 0; l < 4; ++l){
    f32x16 acc0 = {0}, acc1 = {0};
#pragma unroll
    for (int j = 0; j < 16; ++j){ acc0[j] = 0.0f; acc1[j] = 0.0f; }

    const unsigned short* Wh  = WTh + l * 65536;
    const unsigned short* Wl_ = WTl + l * 65536;

    f16x8 bh[2], bl[2];
    bh[0] = LDW(Wh  + bbase);
    bl[0] = LDW(Wl_ + bbase);

#pragma unroll
    for (int ks = 0; ks < 16; ++ks){
      const int cur = ks & 1, nxt = cur ^ 1;
      if (ks < 15){
        bh[nxt] = LDW(Wh  + bbase + (ks + 1) * 512);
        bl[nxt] = LDW(Wl_ + bbase + (ks + 1) * 512);
      }
      const int kc = ks * 16 + lhi * 8;
      f16x8 ah0 = LDW(&Ah[ACOL(l31,      kc)]);
      f16x8 al0 = LDW(&Al[ACOL(l31,      kc)]);
      f16x8 ah1 = LDW(&Ah[ACOL(32 + l31, kc)]);
      f16x8 al1 = LDW(&Al[ACOL(32 + l31, kc)]);
      acc0 = __builtin_amdgcn_mfma_f32_32x32x16_f16(ah0, bh[cur], acc0, 0, 0, 0);
      acc1 = __builtin_amdgcn_mfma_f32_32x32x16_f16(ah1, bh[cur], acc1, 0, 0, 0);
      acc0 = __builtin_amdgcn_mfma_f32_32x32x16_f16(al0, bh[cur], acc0, 0, 0, 0);
      acc1 = __builtin_amdgcn_mfma_f32_32x32x16_f16(al1, bh[cur], acc1, 0, 0, 0);
      acc0 = __builtin_amdgcn_mfma_f32_32x32x16_f16(ah0, bl[cur], acc0, 0, 0, 0);
      acc1 = __builtin_amdgcn_mfma_f32_32x32x16_f16(ah1, bl[cur], acc1, 0, 0, 0);
    }
    __syncthreads();   // all reads of tiles done before overwrite

    // epilogue: C/D layout (m74/m101): col=l31, row=(reg&3)+8*(reg>>2)+4*lhi
    const float bs = bsv[l];
#define EPI32(ACC, RBASE) do { \
      _Pragma("unroll") \
      for (int reg = 0; reg < 16; ++reg){ \
        const int row = (RBASE) + 4 * lhi + 8 * (reg >> 2) + (reg & 3); \
        float v = fmaf((ACC)[reg] + bs, gmv, btv); \
        float gg = fast_gelu(v); \
        unsigned short h, lo; \
        split16(gg, h, lo); \
        Ah[ACOL(row, mycol)] = h; \
        Al[ACOL(row, mycol)] = lo; \
      } } while(0)
    EPI32(acc0, 0);
    EPI32(acc1, 32);
#undef EPI32
    __syncthreads();
  }

  // ---------------- phase 2: output head (256 -> 3) + tanh (16x16 path) ----
  if (wv < 4){
    f32x4 ao = (f32x4){0.0f, 0.0f, 0.0f, 0.0f};
#pragma unroll
    for (int ks = 0; ks < 8; ++ks){
      const int kc = ks * 32 + lg * 8;
      f16x8 va = LDW(&Ah[ACOL(wv * 16 + l15, kc)]);
      f16x8 vl = LDW(&Al[ACOL(wv * 16 + l15, kc)]);
      f16x8 vb = LDW(&WoT[(ks * 64 + lane) * 8]);
      ao = __builtin_amdgcn_mfma_f32_16x16x32_f16(va, vb, ao, 0, 0, 0);
      ao = __builtin_amdgcn_mfma_f32_16x16x32_f16(vl, vb, ao, 0, 0, 0);
    }
    if (l15 < 3){
      const float bo = bout[l15];
#pragma unroll
      for (int rg = 0; rg < 4; ++rg){
        const int row = wv * 16 + lg * 4 + rg;
        out[((size_t)bi * 16384 + n0 + row) * 3 + l15] = fast_tanh(ao[rg] + bo);
      }
    }
  }
}

// ------------------------------- launch --------------------------------------
extern "C" void kernel_launch(void* const* d_in, const int* in_sizes, int n_in,
                              void* d_out, int out_size, void* d_ws, size_t ws_size,
                              hipStream_t stream){
  (void)in_sizes; (void)n_in; (void)out_size; (void)ws_size;
  const float* fg     = (const float*)d_in[0];
  const float* cv     = (const float*)d_in[1];
  const float* coords = (const float*)d_in[2];
  const float* Wc     = (const float*)d_in[3];
  const float* bc     = (const float*)d_in[4];
  const float* W0     = (const float*)d_in[5];
  const float* b0     = (const float*)d_in[6];
  const float* W1     = (const float*)d_in[7];
  const float* b1     = (const float*)d_in[8];
  const float* W2     = (const float*)d_in[9];
  const float* b2     = (const float*)d_in[10];
  const float* W3     = (const float*)d_in[11];
  const float* b3     = (const float*)d_in[12];
  const float* Wout   = (const float*)d_in[13];
  const float* bout   = (const float*)d_in[14];

  char* ws = (char*)d_ws;
  float*          p1    = (float*)(ws);                    // 8*32*32*64 f32 = 2 MB
  float*          p2    = (float*)(ws + 2097152);          // 8*16*16*64 f32 = 512 KB
  unsigned short* WTh   = (unsigned short*)(ws + 2621440); // 4*256*256 f16 = 512 KB
  unsigned short* WTl   = (unsigned short*)(ws + 3145728); // 512 KB
  unsigned short* WoT   = (unsigned short*)(ws + 3670016); // 8*64*8 f16
  float*          gam   = (float*)(ws + 3678208);          // 8*256 f32
  float*          bet   = (float*)(ws + 3686400);          // 8*256 f32
  float*          outp  = (float*)d_out;

  pyr_kernel<<<dim3(2048), dim3(256), 0, stream>>>(fg, p1, 32, 32, 2.0f);
  pyr_kernel<<<dim3(512),  dim3(256), 0, stream>>>(fg, p2, 16, 16, 4.0f);
  prep_wt  <<<dim3(1024),  dim3(256), 0, stream>>>(W0, W1, W2, W3, WTh, WTl);
  prep_misc<<<dim3(32),    dim3(256), 0, stream>>>(cv, Wc, bc, Wout, gam, bet, WoT);
  dec_main <<<dim3(2048),  dim3(512), 0, stream>>>(fg, coords, p1, p2, WTh, WTl, WoT,
                                                   gam, bet, b0, b1, b2, b3, bout, outp);
}

// Round 14
// 275.817 us; speedup vs baseline: 1.1921x; 1.1631x over previous
//
#include <hip/hip_runtime.h>
#include <math.h>

typedef _Float16 f16x8 __attribute__((ext_vector_type(8)));
typedef float f32x4 __attribute__((ext_vector_type(4)));
typedef float f32x16 __attribute__((ext_vector_type(16)));
typedef unsigned short us8 __attribute__((ext_vector_type(8)));

#define PI_F 3.14159265358979323846f

__device__ __forceinline__ void split16(float f, unsigned short& h, unsigned short& l){
  _Float16 hi = (_Float16)f;
  _Float16 lo = (_Float16)(f - (float)hi);
  h = __builtin_bit_cast(unsigned short, hi);
  l = __builtin_bit_cast(unsigned short, lo);
}

__device__ __forceinline__ float fast_gelu(float v){
  float u2 = v * v;
  float z  = v * fmaf(u2, 0.03567740814f, 0.7978845608f);
  float e  = __builtin_amdgcn_exp2f(z * 2.885390082f);   // 2*log2(e)
  float r  = __builtin_amdgcn_rcpf(e + 1.0f);
  return v - v * r;
}

__device__ __forceinline__ float fast_tanh(float v){
  float e = __builtin_amdgcn_exp2f(v * 2.885390082f);
  float r = __builtin_amdgcn_rcpf(e + 1.0f);
  return 1.0f - 2.0f * r;
}

// LDS tile addressing in ushort units, XOR swizzle for bank balance
#define ACOL(rr,cc) (((rr) << 8) + ((cc) ^ ((((rr) & 15)) << 3)))

#define LDW(ptr) __builtin_bit_cast(f16x8, *reinterpret_cast<const us8*>(ptr))

// ---------------- pyramid (jax.image.resize bilinear, antialias=True) -------
__global__ void pyr_kernel(const float* __restrict__ fg, float* __restrict__ out,
                           int Ho, int Wo, float inv_scale){
  int idx = blockIdx.x * blockDim.x + threadIdx.x;
  int total = 8 * Ho * Wo * 64;
  if (idx >= total) return;
  int c  = idx & 63;
  int xy = idx >> 6;
  int x  = xy % Wo;
  int y  = (xy / Wo) % Ho;
  int b  = xy / (Wo * Ho);
  float cyc = inv_scale * (y + 0.5f) - 0.5f;
  float cxc = inv_scale * (x + 0.5f) - 0.5f;
  int iy0 = (int)ceilf(cyc - inv_scale); if (iy0 < 0) iy0 = 0;
  int iy1 = (int)floorf(cyc + inv_scale); if (iy1 > 63) iy1 = 63;
  int ix0 = (int)ceilf(cxc - inv_scale); if (ix0 < 0) ix0 = 0;
  int ix1 = (int)floorf(cxc + inv_scale); if (ix1 > 63) ix1 = 63;
  float rinv = 1.0f / inv_scale;
  float wxs = 0.0f;
  for (int ix = ix0; ix <= ix1; ++ix){
    float w = 1.0f - fabsf(ix - cxc) * rinv;
    if (w > 0.0f) wxs += w;
  }
  float wys = 0.0f, acc = 0.0f;
  for (int iy = iy0; iy <= iy1; ++iy){
    float wy = 1.0f - fabsf(iy - cyc) * rinv;
    if (wy <= 0.0f) continue;
    wys += wy;
    const float* rowp = fg + (((b * 64) + iy) * 64) * 64 + c;
    for (int ix = ix0; ix <= ix1; ++ix){
      float wx = 1.0f - fabsf(ix - cxc) * rinv;
      if (wx <= 0.0f) continue;
      acc += wy * wx * rowp[ix * 64];
    }
  }
  out[idx] = acc / (wys * wxs);
}

// ------------- weight prep: pre-tiled per-lane 32x32x16 MFMA fragments ------
// WT[l][cfg][ks][lane][e]: col = cfg*32 + (lane&31), k = ks*16 + (lane>>5)*8 + e
// (cfg in [0,8), ks in [0,16)) — same slot-consistent map used for A fragments.
// layer0 k-remap: k<42 -> W0 row k; 42..47 pad; 48..239 -> row k-6; 240..255 pad
__global__ void prep_wt(const float* __restrict__ W0, const float* __restrict__ W1,
                        const float* __restrict__ W2, const float* __restrict__ W3,
                        unsigned short* __restrict__ WTh, unsigned short* __restrict__ WTl){
  int idx = blockIdx.x * 256 + threadIdx.x;      // < 262144
  int l    = idx >> 16;
  int rem  = idx & 65535;
  int cfg  = rem >> 13;          // 0..7
  int ks   = (rem >> 9) & 15;    // 0..15
  int lane = (rem >> 3) & 63;
  int e    = idx & 7;
  int col  = cfg * 32 + (lane & 31);
  int k    = ks * 16 + (lane >> 5) * 8 + e;
  float v;
  if (l == 0){
    int row; bool valid;
    if (k < 42)                 { row = k;     valid = true; }
    else if (k >= 48 && k < 240){ row = k - 6; valid = true; }
    else                        { row = 0;     valid = false; }
    v = valid ? W0[row * 256 + col] : 0.0f;
  } else {
    const float* W = (l == 1) ? W1 : ((l == 2) ? W2 : W3);
    v = W[k * 256 + col];
  }
  unsigned short h, lo;
  split16(v, h, lo);
  WTh[idx] = h;
  WTl[idx] = lo;    // written but unused this round (weights f16-only)
}

// ------------- FiLM params + Wout tiled fragments (16x16 head, unchanged) ---
__global__ void prep_misc(const float* __restrict__ cv, const float* __restrict__ Wc,
                          const float* __restrict__ bc, const float* __restrict__ Wout,
                          float* __restrict__ gamma, float* __restrict__ beta,
                          unsigned short* __restrict__ WoT){
  int idx = blockIdx.x * 256 + threadIdx.x;      // < 8192
  if (idx < 4096){
    int b = idx >> 9, j = idx & 511;
    float a = bc[j];
    for (int c = 0; c < 64; ++c) a += cv[b * 64 + c] * Wc[c * 512 + j];
    if (j < 256) gamma[b * 256 + j] = a + 1.0f;
    else         beta[b * 256 + (j - 256)] = a;
  } else {
    int j = idx - 4096;                // WoT[ks][lane][e]
    int ks = j >> 9, lane = (j >> 3) & 63, e = j & 7;
    int col = lane & 15;
    int k = ks * 32 + (lane >> 4) * 8 + e;
    float v = (col < 3) ? Wout[k * 3 + col] : 0.0f;
    _Float16 h = (_Float16)v;
    WoT[j] = __builtin_bit_cast(unsigned short, h);
  }
}

// ------------------------------- main ---------------------------------------
// R13 config (512thr, (512,2), 64-row tile, 8 waves/CU) with:
//  (1) weights f16-only (ah*bh + al*bh; drops ah*bl — weight dequant err ~1e-3
//      final, under bf16 half-quantum), halving MFMA count and B traffic;
//  (2) wave re-tile 2rg x 4cg: each wave computes 32 rows x 64 cols, reading
//      only its 32-row A slice — halves redundant A-tile LDS reads.
// 32x32 MFMA wiring identical to R13 (HW-validated); prep layouts unchanged.
__global__ __launch_bounds__(512, 2)
void dec_main(const float* __restrict__ fg, const float* __restrict__ coords,
              const float* __restrict__ p1, const float* __restrict__ p2,
              const unsigned short* __restrict__ WTh, const unsigned short* __restrict__ WTl,
              const unsigned short* __restrict__ WoT,
              const float* __restrict__ gamma, const float* __restrict__ beta,
              const float* __restrict__ b0, const float* __restrict__ b1,
              const float* __restrict__ b2, const float* __restrict__ b3,
              const float* __restrict__ bout, float* __restrict__ out){
  __shared__ __align__(16) unsigned short Ah[64 * 256];  // 32 KB hi tile
  __shared__ __align__(16) unsigned short Al[64 * 256];  // 32 KB lo tile

  const int t  = threadIdx.x;
  const int bi = blockIdx.x >> 8;           // image 0..7   (R4-validated decode)
  const int n0 = (blockIdx.x & 255) * 64;   // first coord row of this block

  const int lane = t & 63;
  const int wv   = t >> 6;         // 0..7
  const int l15  = lane & 15;      // head (16x16) lane decode
  const int lg   = lane >> 4;
  const int l31  = lane & 31;      // 32x32 lane decode
  const int lhi  = lane >> 5;      // 0/1

  const int rg   = wv >> 2;        // row group 0/1  -> rows rg*32..+32
  const int cg   = wv & 3;         // col group 0..3 -> cols cg*64..+64
  const int arow = rg * 32 + l31;  // this lane's A row

  // FiLM params + biases: 2 columns per lane (col = cg*64 + cf*32 + l31)
  float gmv[2], btv[2], bsv[4][2];
#pragma unroll
  for (int cf = 0; cf < 2; ++cf){
    const int col = cg * 64 + cf * 32 + l31;
    gmv[cf] = gamma[bi * 256 + col];
    btv[cf] = beta[bi * 256 + col];
    bsv[0][cf] = b0[col]; bsv[1][cf] = b1[col];
    bsv[2][cf] = b2[col]; bsv[3][cf] = b3[col];
  }

  // ---------------- phase 0: build features (split f16, swizzled) ----------
  // R4-validated body verbatim, gated to t<256 (4 threads/row over 64 rows)
  if (t < 256){
    const int r = t >> 2, q = t & 3;
    const int n = n0 + r;
    const float cy = coords[2 * n], cx = coords[2 * n + 1];

    if (q == 0){
      float e[48];
      e[0] = cy; e[1] = cx;
#pragma unroll
      for (int i = 0; i < 10; ++i){
        float f = PI_F * (float)(1 << i);
        float sy, cyv, sx, cxv;
        sincosf(cy * f, &sy, &cyv);
        sincosf(cx * f, &sx, &cxv);
        e[2 + 4 * i] = sy;
        e[3 + 4 * i] = sx;
        e[4 + 4 * i] = cyv;
        e[5 + 4 * i] = cxv;
      }
#pragma unroll
      for (int j = 42; j < 48; ++j) e[j] = 0.0f;
#pragma unroll
      for (int u = 0; u < 6; ++u){
        us8 vh, vl;
#pragma unroll
        for (int j = 0; j < 8; ++j){
          unsigned short h, l;
          split16(e[8 * u + j], h, l);
          vh[j] = h; vl[j] = l;
        }
        *reinterpret_cast<us8*>(&Ah[ACOL(r, u * 8)]) = vh;
        *reinterpret_cast<us8*>(&Al[ACOL(r, u * 8)]) = vl;
      }
    }
    if (q == 1){   // zero pad cols 240..255
      us8 z = {0,0,0,0,0,0,0,0};
      *reinterpret_cast<us8*>(&Ah[ACOL(r, 240)]) = z;
      *reinterpret_cast<us8*>(&Ah[ACOL(r, 248)]) = z;
      *reinterpret_cast<us8*>(&Al[ACOL(r, 240)]) = z;
      *reinterpret_cast<us8*>(&Al[ACOL(r, 248)]) = z;
    }

    // bilinear sample 16 channels per thread from each pyramid level
#pragma unroll
    for (int L = 0; L < 3; ++L){
      const int HL = 64 >> L;
      const float* g = (L == 0) ? fg : ((L == 1) ? p1 : p2);
      float yy = (cy + 1.0f) * 0.5f * (HL - 1);
      float xx = (cx + 1.0f) * 0.5f * (HL - 1);
      float y0f = floorf(yy), x0f = floorf(xx);
      float wy = yy - y0f, wx = xx - x0f;
      int y0 = (int)y0f, x0 = (int)x0f;
      y0 = min(max(y0, 0), HL - 1); x0 = min(max(x0, 0), HL - 1);
      int y1 = min(y0 + 1, HL - 1), x1 = min(x0 + 1, HL - 1);
      const int c0 = q * 16;
      const float* g00 = g + (((bi * HL + y0) * HL) + x0) * 64 + c0;
      const float* g01 = g + (((bi * HL + y0) * HL) + x1) * 64 + c0;
      const float* g10 = g + (((bi * HL + y1) * HL) + x0) * 64 + c0;
      const float* g11 = g + (((bi * HL + y1) * HL) + x1) * 64 + c0;
      float w00 = (1 - wy) * (1 - wx), w01 = (1 - wy) * wx;
      float w10 = wy * (1 - wx),       w11 = wy * wx;
      float o[16];
#pragma unroll
      for (int u = 0; u < 4; ++u){
        float4 v0 = *reinterpret_cast<const float4*>(g00 + 4 * u);
        float4 v1 = *reinterpret_cast<const float4*>(g01 + 4 * u);
        float4 v2 = *reinterpret_cast<const float4*>(g10 + 4 * u);
        float4 v3 = *reinterpret_cast<const float4*>(g11 + 4 * u);
        o[4*u+0] = w00*v0.x + w01*v1.x + w10*v2.x + w11*v3.x;
        o[4*u+1] = w00*v0.y + w01*v1.y + w10*v2.y + w11*v3.y;
        o[4*u+2] = w00*v0.z + w01*v1.z + w10*v2.z + w11*v3.z;
        o[4*u+3] = w00*v0.w + w01*v1.w + w10*v2.w + w11*v3.w;
      }
      us8 h0, h1, l0, l1;
#pragma unroll
      for (int j = 0; j < 8; ++j){
        unsigned short h, l;
        split16(o[j], h, l);      h0[j] = h; l0[j] = l;
        split16(o[8 + j], h, l);  h1[j] = h; l1[j] = l;
      }
      const int colb = 48 + 64 * L + 16 * q;
      *reinterpret_cast<us8*>(&Ah[ACOL(r, colb)])     = h0;
      *reinterpret_cast<us8*>(&Ah[ACOL(r, colb + 8)]) = h1;
      *reinterpret_cast<us8*>(&Al[ACOL(r, colb)])     = l0;
      *reinterpret_cast<us8*>(&Al[ACOL(r, colb + 8)]) = l1;
    }
  }
  __syncthreads();

  // ---------------- phase 1: 4 FiLM-gelu MLP layers (32x32x16) -------------
  // wave (rg,cg) computes rows rg*32..+32 x cols cg*64..+64 (cfg = cg*2+{0,1})
  const int b0off = (cg * 2)     * 8192 + lane * 8;
  const int b1off = (cg * 2 + 1) * 8192 + lane * 8;

  for (int l = 0; l < 4; ++l){
    f32x16 accA, accB;
#pragma unroll
    for (int j = 0; j < 16; ++j){ accA[j] = 0.0f; accB[j] = 0.0f; }

    const unsigned short* Wh = WTh + l * 65536;

    f16x8 bf0[2], bf1[2];
    bf0[0] = LDW(Wh + b0off);
    bf1[0] = LDW(Wh + b1off);

#pragma unroll
    for (int ks = 0; ks < 16; ++ks){
      const int cur = ks & 1, nxt = cur ^ 1;
      if (ks < 15){
        bf0[nxt] = LDW(Wh + b0off + (ks + 1) * 512);
        bf1[nxt] = LDW(Wh + b1off + (ks + 1) * 512);
      }
      const int kc = ks * 16 + lhi * 8;
      f16x8 ah = LDW(&Ah[ACOL(arow, kc)]);
      f16x8 al = LDW(&Al[ACOL(arow, kc)]);
      accA = __builtin_amdgcn_mfma_f32_32x32x16_f16(ah, bf0[cur], accA, 0, 0, 0);
      accB = __builtin_amdgcn_mfma_f32_32x32x16_f16(ah, bf1[cur], accB, 0, 0, 0);
      accA = __builtin_amdgcn_mfma_f32_32x32x16_f16(al, bf0[cur], accA, 0, 0, 0);
      accB = __builtin_amdgcn_mfma_f32_32x32x16_f16(al, bf1[cur], accB, 0, 0, 0);
    }
    __syncthreads();   // all reads of tiles done before overwrite

    // epilogue: C/D layout (m74/m101): col=l31, row=(reg&3)+8*(reg>>2)+4*lhi
    const float bsA = bsv[l][0], bsB = bsv[l][1];
#define EPI32(ACC, CF, BS) do { \
      const int col_ = cg * 64 + (CF) * 32 + l31; \
      _Pragma("unroll") \
      for (int reg = 0; reg < 16; ++reg){ \
        const int row_ = rg * 32 + 4 * lhi + 8 * (reg >> 2) + (reg & 3); \
        float v = fmaf((ACC)[reg] + (BS), gmv[CF], btv[CF]); \
        float gg = fast_gelu(v); \
        unsigned short h, lo; \
        split16(gg, h, lo); \
        Ah[ACOL(row_, col_)] = h; \
        Al[ACOL(row_, col_)] = lo; \
      } } while(0)
    EPI32(accA, 0, bsA);
    EPI32(accB, 1, bsB);
#undef EPI32
    __syncthreads();
  }

  // ---------------- phase 2: output head (256 -> 3) + tanh (16x16 path) ----
  if (wv < 4){
    f32x4 ao = (f32x4){0.0f, 0.0f, 0.0f, 0.0f};
#pragma unroll
    for (int ks = 0; ks < 8; ++ks){
      const int kc = ks * 32 + lg * 8;
      f16x8 va = LDW(&Ah[ACOL(wv * 16 + l15, kc)]);
      f16x8 vl = LDW(&Al[ACOL(wv * 16 + l15, kc)]);
      f16x8 vb = LDW(&WoT[(ks * 64 + lane) * 8]);
      ao = __builtin_amdgcn_mfma_f32_16x16x32_f16(va, vb, ao, 0, 0, 0);
      ao = __builtin_amdgcn_mfma_f32_16x16x32_f16(vl, vb, ao, 0, 0, 0);
    }
    if (l15 < 3){
      const float bo = bout[l15];
#pragma unroll
      for (int rg2 = 0; rg2 < 4; ++rg2){
        const int row = wv * 16 + lg * 4 + rg2;
        out[((size_t)bi * 16384 + n0 + row) * 3 + l15] = fast_tanh(ao[rg2] + bo);
      }
    }
  }
}

// ------------------------------- launch --------------------------------------
extern "C" void kernel_launch(void* const* d_in, const int* in_sizes, int n_in,
                              void* d_out, int out_size, void* d_ws, size_t ws_size,
                              hipStream_t stream){
  (void)in_sizes; (void)n_in; (void)out_size; (void)ws_size;
  const float* fg     = (const float*)d_in[0];
  const float* cv     = (const float*)d_in[1];
  const float* coords = (const float*)d_in[2];
  const float* Wc     = (const float*)d_in[3];
  const float* bc     = (const float*)d_in[4];
  const float* W0     = (const float*)d_in[5];
  const float* b0     = (const float*)d_in[6];
  const float* W1     = (const float*)d_in[7];
  const float* b1     = (const float*)d_in[8];
  const float* W2     = (const float*)d_in[9];
  const float* b2     = (const float*)d_in[10];
  const float* W3     = (const float*)d_in[11];
  const float* b3     = (const float*)d_in[12];
  const float* Wout   = (const float*)d_in[13];
  const float* bout   = (const float*)d_in[14];

  char* ws = (char*)d_ws;
  float*          p1    = (float*)(ws);                    // 8*32*32*64 f32 = 2 MB
  float*          p2    = (float*)(ws + 2097152);          // 8*16*16*64 f32 = 512 KB
  unsigned short* WTh   = (unsigned short*)(ws + 2621440); // 4*256*256 f16 = 512 KB
  unsigned short* WTl   = (unsigned short*)(ws + 3145728); // 512 KB (unused)
  unsigned short* WoT   = (unsigned short*)(ws + 3670016); // 8*64*8 f16
  float*          gam   = (float*)(ws + 3678208);          // 8*256 f32
  float*          bet   = (float*)(ws + 3686400);          // 8*256 f32
  float*          outp  = (float*)d_out;

  pyr_kernel<<<dim3(2048), dim3(256), 0, stream>>>(fg, p1, 32, 32, 2.0f);
  pyr_kernel<<<dim3(512),  dim3(256), 0, stream>>>(fg, p2, 16, 16, 4.0f);
  prep_wt  <<<dim3(1024),  dim3(256), 0, stream>>>(W0, W1, W2, W3, WTh, WTl);
  prep_misc<<<dim3(32),    dim3(256), 0, stream>>>(cv, Wc, bc, Wout, gam, bet, WoT);
  dec_main <<<dim3(2048),  dim3(512), 0, stream>>>(fg, coords, p1, p2, WTh, WTl, WoT,
                                                   gam, bet, b0, b1, b2, b3, bout, outp);
}

// Round 15
// 257.656 us; speedup vs baseline: 1.2761x; 1.0705x over previous
//
#include <hip/hip_runtime.h>
#include <math.h>

typedef _Float16 f16x8 __attribute__((ext_vector_type(8)));
typedef float f32x4 __attribute__((ext_vector_type(4)));
typedef float f32x16 __attribute__((ext_vector_type(16)));
typedef unsigned short us8 __attribute__((ext_vector_type(8)));

#define PI_F 3.14159265358979323846f

__device__ __forceinline__ void split16(float f, unsigned short& h, unsigned short& l){
  _Float16 hi = (_Float16)f;
  _Float16 lo = (_Float16)(f - (float)hi);
  h = __builtin_bit_cast(unsigned short, hi);
  l = __builtin_bit_cast(unsigned short, lo);
}

__device__ __forceinline__ float fast_gelu(float v){
  float u2 = v * v;
  float z  = v * fmaf(u2, 0.03567740814f, 0.7978845608f);
  float e  = __builtin_amdgcn_exp2f(z * 2.885390082f);   // 2*log2(e)
  float r  = __builtin_amdgcn_rcpf(e + 1.0f);
  return v - v * r;
}

__device__ __forceinline__ float fast_tanh(float v){
  float e = __builtin_amdgcn_exp2f(v * 2.885390082f);
  float r = __builtin_amdgcn_rcpf(e + 1.0f);
  return 1.0f - 2.0f * r;
}

// LDS tile addressing in ushort units, XOR swizzle for bank balance
#define ACOL(rr,cc) (((rr) << 8) + ((cc) ^ ((((rr) & 15)) << 3)))

#define LDW(ptr) __builtin_bit_cast(f16x8, *reinterpret_cast<const us8*>(ptr))

// ---------------- pyramid (jax.image.resize bilinear, antialias=True) -------
__global__ void pyr_kernel(const float* __restrict__ fg, float* __restrict__ out,
                           int Ho, int Wo, float inv_scale){
  int idx = blockIdx.x * blockDim.x + threadIdx.x;
  int total = 8 * Ho * Wo * 64;
  if (idx >= total) return;
  int c  = idx & 63;
  int xy = idx >> 6;
  int x  = xy % Wo;
  int y  = (xy / Wo) % Ho;
  int b  = xy / (Wo * Ho);
  float cyc = inv_scale * (y + 0.5f) - 0.5f;
  float cxc = inv_scale * (x + 0.5f) - 0.5f;
  int iy0 = (int)ceilf(cyc - inv_scale); if (iy0 < 0) iy0 = 0;
  int iy1 = (int)floorf(cyc + inv_scale); if (iy1 > 63) iy1 = 63;
  int ix0 = (int)ceilf(cxc - inv_scale); if (ix0 < 0) ix0 = 0;
  int ix1 = (int)floorf(cxc + inv_scale); if (ix1 > 63) ix1 = 63;
  float rinv = 1.0f / inv_scale;
  float wxs = 0.0f;
  for (int ix = ix0; ix <= ix1; ++ix){
    float w = 1.0f - fabsf(ix - cxc) * rinv;
    if (w > 0.0f) wxs += w;
  }
  float wys = 0.0f, acc = 0.0f;
  for (int iy = iy0; iy <= iy1; ++iy){
    float wy = 1.0f - fabsf(iy - cyc) * rinv;
    if (wy <= 0.0f) continue;
    wys += wy;
    const float* rowp = fg + (((b * 64) + iy) * 64) * 64 + c;
    for (int ix = ix0; ix <= ix1; ++ix){
      float wx = 1.0f - fabsf(ix - cxc) * rinv;
      if (wx <= 0.0f) continue;
      acc += wy * wx * rowp[ix * 64];
    }
  }
  out[idx] = acc / (wys * wxs);
}

// ------------- posenc table: PE[n][48] split f16 (shared across images) -----
__global__ void pe_kernel(const float* __restrict__ coords,
                          unsigned short* __restrict__ peh,
                          unsigned short* __restrict__ pel){
  int idx = blockIdx.x * 256 + threadIdx.x;   // < 196608
  if (idx >= 16384 * 12) return;
  int n = idx / 12, slot = idx % 12;
  const float cy = coords[2 * n], cx = coords[2 * n + 1];
  unsigned short h, l;
  if (slot == 0){
    split16(cy, h, l); peh[n * 48 + 0] = h; pel[n * 48 + 0] = l;
    split16(cx, h, l); peh[n * 48 + 1] = h; pel[n * 48 + 1] = l;
  } else if (slot <= 10){
    int i = slot - 1;
    float f = PI_F * (float)(1 << i);
    float sy, cyv, sx, cxv;
    sincosf(cy * f, &sy, &cyv);
    sincosf(cx * f, &sx, &cxv);
    split16(sy,  h, l); peh[n * 48 + 2 + 4 * i] = h; pel[n * 48 + 2 + 4 * i] = l;
    split16(sx,  h, l); peh[n * 48 + 3 + 4 * i] = h; pel[n * 48 + 3 + 4 * i] = l;
    split16(cyv, h, l); peh[n * 48 + 4 + 4 * i] = h; pel[n * 48 + 4 + 4 * i] = l;
    split16(cxv, h, l); peh[n * 48 + 5 + 4 * i] = h; pel[n * 48 + 5 + 4 * i] = l;
  } else {
#pragma unroll
    for (int j = 42; j < 48; ++j){ peh[n * 48 + j] = 0; pel[n * 48 + j] = 0; }
  }
}

// ------------- weight prep: pre-tiled per-lane 32x32x16 MFMA fragments ------
// WT[l][cfg][ks][lane][e]: col = cfg*32 + (lane&31), k = ks*16 + (lane>>5)*8 + e
// layer0 k-remap: k<42 -> W0 row k; 42..47 pad; 48..239 -> row k-6; 240..255 pad
__global__ void prep_wt(const float* __restrict__ W0, const float* __restrict__ W1,
                        const float* __restrict__ W2, const float* __restrict__ W3,
                        unsigned short* __restrict__ WTh, unsigned short* __restrict__ WTl){
  int idx = blockIdx.x * 256 + threadIdx.x;      // < 262144
  int l    = idx >> 16;
  int rem  = idx & 65535;
  int cfg  = rem >> 13;          // 0..7
  int ks   = (rem >> 9) & 15;    // 0..15
  int lane = (rem >> 3) & 63;
  int e    = idx & 7;
  int col  = cfg * 32 + (lane & 31);
  int k    = ks * 16 + (lane >> 5) * 8 + e;
  float v;
  if (l == 0){
    int row; bool valid;
    if (k < 42)                 { row = k;     valid = true; }
    else if (k >= 48 && k < 240){ row = k - 6; valid = true; }
    else                        { row = 0;     valid = false; }
    v = valid ? W0[row * 256 + col] : 0.0f;
  } else {
    const float* W = (l == 1) ? W1 : ((l == 2) ? W2 : W3);
    v = W[k * 256 + col];
  }
  unsigned short h, lo;
  split16(v, h, lo);
  WTh[idx] = h;
  WTl[idx] = lo;    // unused (weights f16-only) — kept for layout stability
}

// ------------- FiLM params + Wout tiled fragments (16x16 head) --------------
__global__ void prep_misc(const float* __restrict__ cv, const float* __restrict__ Wc,
                          const float* __restrict__ bc, const float* __restrict__ Wout,
                          float* __restrict__ gamma, float* __restrict__ beta,
                          unsigned short* __restrict__ WoT){
  int idx = blockIdx.x * 256 + threadIdx.x;      // < 8192
  if (idx < 4096){
    int b = idx >> 9, j = idx & 511;
    float a = bc[j];
    for (int c = 0; c < 64; ++c) a += cv[b * 64 + c] * Wc[c * 512 + j];
    if (j < 256) gamma[b * 256 + j] = a + 1.0f;
    else         beta[b * 256 + (j - 256)] = a;
  } else {
    int j = idx - 4096;                // WoT[ks][lane][e]
    int ks = j >> 9, lane = (j >> 3) & 63, e = j & 7;
    int col = lane & 15;
    int k = ks * 32 + (lane >> 4) * 8 + e;
    float v = (col < 3) ? Wout[k * 3 + col] : 0.0f;
    _Float16 h = (_Float16)v;
    WoT[j] = __builtin_bit_cast(unsigned short, h);
  }
}

// ------------------------------- main ---------------------------------------
// R14-validated math/tiling (32x32x16, f16 weights, 2rg x 4cg waves) with:
//  (1) double-buffered activation tiles T0/T1 (128 KB LDS): layer l reads
//      T[l&1] while its epilogue writes T[1^(l&1)] — ONE barrier per layer,
//      letting epilogue VALU overlap other waves' K-loop MFMA.
//  (2) posenc from precomputed PE table (if ws large enough) — removes the
//      8x-duplicated serial sincos chain from phase 0.
__global__ __launch_bounds__(512, 2)
void dec_main(const float* __restrict__ fg, const float* __restrict__ coords,
              const float* __restrict__ p1, const float* __restrict__ p2,
              const unsigned short* __restrict__ WTh, const unsigned short* __restrict__ WTl,
              const unsigned short* __restrict__ WoT,
              const unsigned short* __restrict__ peh, const unsigned short* __restrict__ pel,
              const float* __restrict__ gamma, const float* __restrict__ beta,
              const float* __restrict__ b0, const float* __restrict__ b1,
              const float* __restrict__ b2, const float* __restrict__ b3,
              const float* __restrict__ bout, float* __restrict__ out){
  __shared__ __align__(16) unsigned short Ah0[64 * 256];  // 32 KB  T0 hi
  __shared__ __align__(16) unsigned short Al0[64 * 256];  // 32 KB  T0 lo
  __shared__ __align__(16) unsigned short Ah1[64 * 256];  // 32 KB  T1 hi
  __shared__ __align__(16) unsigned short Al1[64 * 256];  // 32 KB  T1 lo

  const int t  = threadIdx.x;
  const int bi = blockIdx.x >> 8;           // image 0..7   (R4-validated decode)
  const int n0 = (blockIdx.x & 255) * 64;   // first coord row of this block

  const int lane = t & 63;
  const int wv   = t >> 6;         // 0..7
  const int l15  = lane & 15;      // head (16x16) lane decode
  const int lg   = lane >> 4;
  const int l31  = lane & 31;      // 32x32 lane decode
  const int lhi  = lane >> 5;      // 0/1

  const int rg   = wv >> 2;        // row group 0/1  -> rows rg*32..+32
  const int cg   = wv & 3;         // col group 0..3 -> cols cg*64..+64
  const int arow = rg * 32 + l31;  // this lane's A row

  // FiLM params + biases: 2 columns per lane (col = cg*64 + cf*32 + l31)
  float gmv[2], btv[2], bsv[4][2];
#pragma unroll
  for (int cf = 0; cf < 2; ++cf){
    const int col = cg * 64 + cf * 32 + l31;
    gmv[cf] = gamma[bi * 256 + col];
    btv[cf] = beta[bi * 256 + col];
    bsv[0][cf] = b0[col]; bsv[1][cf] = b1[col];
    bsv[2][cf] = b2[col]; bsv[3][cf] = b3[col];
  }

  // ---------------- phase 0: build features into T0 (split f16, swizzled) --
  // R4-validated body, gated to t<256 (4 threads/row over 64 rows); posenc
  // block replaced by PE-table loads when available (identical store pattern).
  if (t < 256){
    const int r = t >> 2, q = t & 3;
    const int n = n0 + r;
    const float cy = coords[2 * n], cx = coords[2 * n + 1];

    if (q == 0){
      if (peh){
        const unsigned short* ph = peh + (size_t)n * 48;
        const unsigned short* pl = pel + (size_t)n * 48;
#pragma unroll
        for (int u = 0; u < 6; ++u){
          us8 vh = *reinterpret_cast<const us8*>(ph + u * 8);
          us8 vl = *reinterpret_cast<const us8*>(pl + u * 8);
          *reinterpret_cast<us8*>(&Ah0[ACOL(r, u * 8)]) = vh;
          *reinterpret_cast<us8*>(&Al0[ACOL(r, u * 8)]) = vl;
        }
      } else {
        float e[48];
        e[0] = cy; e[1] = cx;
#pragma unroll
        for (int i = 0; i < 10; ++i){
          float f = PI_F * (float)(1 << i);
          float sy, cyv, sx, cxv;
          sincosf(cy * f, &sy, &cyv);
          sincosf(cx * f, &sx, &cxv);
          e[2 + 4 * i] = sy;
          e[3 + 4 * i] = sx;
          e[4 + 4 * i] = cyv;
          e[5 + 4 * i] = cxv;
        }
#pragma unroll
        for (int j = 42; j < 48; ++j) e[j] = 0.0f;
#pragma unroll
        for (int u = 0; u < 6; ++u){
          us8 vh, vl;
#pragma unroll
          for (int j = 0; j < 8; ++j){
            unsigned short h, l;
            split16(e[8 * u + j], h, l);
            vh[j] = h; vl[j] = l;
          }
          *reinterpret_cast<us8*>(&Ah0[ACOL(r, u * 8)]) = vh;
          *reinterpret_cast<us8*>(&Al0[ACOL(r, u * 8)]) = vl;
        }
      }
    }
    if (q == 1){   // zero pad cols 240..255
      us8 z = {0,0,0,0,0,0,0,0};
      *reinterpret_cast<us8*>(&Ah0[ACOL(r, 240)]) = z;
      *reinterpret_cast<us8*>(&Ah0[ACOL(r, 248)]) = z;
      *reinterpret_cast<us8*>(&Al0[ACOL(r, 240)]) = z;
      *reinterpret_cast<us8*>(&Al0[ACOL(r, 248)]) = z;
    }

    // bilinear sample 16 channels per thread from each pyramid level
#pragma unroll
    for (int L = 0; L < 3; ++L){
      const int HL = 64 >> L;
      const float* g = (L == 0) ? fg : ((L == 1) ? p1 : p2);
      float yy = (cy + 1.0f) * 0.5f * (HL - 1);
      float xx = (cx + 1.0f) * 0.5f * (HL - 1);
      float y0f = floorf(yy), x0f = floorf(xx);
      float wy = yy - y0f, wx = xx - x0f;
      int y0 = (int)y0f, x0 = (int)x0f;
      y0 = min(max(y0, 0), HL - 1); x0 = min(max(x0, 0), HL - 1);
      int y1 = min(y0 + 1, HL - 1), x1 = min(x0 + 1, HL - 1);
      const int c0 = q * 16;
      const float* g00 = g + (((bi * HL + y0) * HL) + x0) * 64 + c0;
      const float* g01 = g + (((bi * HL + y0) * HL) + x1) * 64 + c0;
      const float* g10 = g + (((bi * HL + y1) * HL) + x0) * 64 + c0;
      const float* g11 = g + (((bi * HL + y1) * HL) + x1) * 64 + c0;
      float w00 = (1 - wy) * (1 - wx), w01 = (1 - wy) * wx;
      float w10 = wy * (1 - wx),       w11 = wy * wx;
      float o[16];
#pragma unroll
      for (int u = 0; u < 4; ++u){
        float4 v0 = *reinterpret_cast<const float4*>(g00 + 4 * u);
        float4 v1 = *reinterpret_cast<const float4*>(g01 + 4 * u);
        float4 v2 = *reinterpret_cast<const float4*>(g10 + 4 * u);
        float4 v3 = *reinterpret_cast<const float4*>(g11 + 4 * u);
        o[4*u+0] = w00*v0.x + w01*v1.x + w10*v2.x + w11*v3.x;
        o[4*u+1] = w00*v0.y + w01*v1.y + w10*v2.y + w11*v3.y;
        o[4*u+2] = w00*v0.z + w01*v1.z + w10*v2.z + w11*v3.z;
        o[4*u+3] = w00*v0.w + w01*v1.w + w10*v2.w + w11*v3.w;
      }
      us8 h0, h1, l0, l1;
#pragma unroll
      for (int j = 0; j < 8; ++j){
        unsigned short h, l;
        split16(o[j], h, l);      h0[j] = h; l0[j] = l;
        split16(o[8 + j], h, l);  h1[j] = h; l1[j] = l;
      }
      const int colb = 48 + 64 * L + 16 * q;
      *reinterpret_cast<us8*>(&Ah0[ACOL(r, colb)])     = h0;
      *reinterpret_cast<us8*>(&Ah0[ACOL(r, colb + 8)]) = h1;
      *reinterpret_cast<us8*>(&Al0[ACOL(r, colb)])     = l0;
      *reinterpret_cast<us8*>(&Al0[ACOL(r, colb + 8)]) = l1;
    }
  }
  __syncthreads();

  // ---------------- phase 1: 4 FiLM-gelu MLP layers (32x32x16) -------------
  // Double-buffered: layer l reads T[l&1], writes T[1^(l&1)]; ONE barrier.
  const int b0off = (cg * 2)     * 8192 + lane * 8;
  const int b1off = (cg * 2 + 1) * 8192 + lane * 8;

#pragma unroll
  for (int l = 0; l < 4; ++l){
    const unsigned short* Rh = (l & 1) ? Ah1 : Ah0;   // read tile
    const unsigned short* Rl = (l & 1) ? Al1 : Al0;
    unsigned short*       Wh_t = (l & 1) ? Ah0 : Ah1; // write tile
    unsigned short*       Wl_t = (l & 1) ? Al0 : Al1;

    f32x16 accA, accB;
#pragma unroll
    for (int j = 0; j < 16; ++j){ accA[j] = 0.0f; accB[j] = 0.0f; }

    const unsigned short* Wh = WTh + l * 65536;

    f16x8 bf0[2], bf1[2];
    bf0[0] = LDW(Wh + b0off);
    bf1[0] = LDW(Wh + b1off);

#pragma unroll
    for (int ks = 0; ks < 16; ++ks){
      const int cur = ks & 1, nxt = cur ^ 1;
      if (ks < 15){
        bf0[nxt] = LDW(Wh + b0off + (ks + 1) * 512);
        bf1[nxt] = LDW(Wh + b1off + (ks + 1) * 512);
      }
      const int kc = ks * 16 + lhi * 8;
      f16x8 ah = LDW(&Rh[ACOL(arow, kc)]);
      f16x8 al = LDW(&Rl[ACOL(arow, kc)]);
      accA = __builtin_amdgcn_mfma_f32_32x32x16_f16(ah, bf0[cur], accA, 0, 0, 0);
      accB = __builtin_amdgcn_mfma_f32_32x32x16_f16(ah, bf1[cur], accB, 0, 0, 0);
      accA = __builtin_amdgcn_mfma_f32_32x32x16_f16(al, bf0[cur], accA, 0, 0, 0);
      accB = __builtin_amdgcn_mfma_f32_32x32x16_f16(al, bf1[cur], accB, 0, 0, 0);
    }
    // no barrier here: epilogue writes the OTHER tile (disjoint), so VALU
    // epilogue of this wave overlaps K-loop MFMA of slower waves.

    const float bsA = bsv[l][0], bsB = bsv[l][1];
#define EPI32(ACC, CF, BS) do { \
      const int col_ = cg * 64 + (CF) * 32 + l31; \
      _Pragma("unroll") \
      for (int reg = 0; reg < 16; ++reg){ \
        const int row_ = rg * 32 + 4 * lhi + 8 * (reg >> 2) + (reg & 3); \
        float v = fmaf((ACC)[reg] + (BS), gmv[CF], btv[CF]); \
        float gg = fast_gelu(v); \
        unsigned short h, lo; \
        split16(gg, h, lo); \
        Wh_t[ACOL(row_, col_)] = h; \
        Wl_t[ACOL(row_, col_)] = lo; \
      } } while(0)
    EPI32(accA, 0, bsA);
    EPI32(accB, 1, bsB);
#undef EPI32
    __syncthreads();   // writes to T[next] visible before next layer reads it
  }

  // ---------------- phase 2: output head (256 -> 3) + tanh (16x16 path) ----
  // Final activations in T0 (l=3 wrote T0).
  if (wv < 4){
    f32x4 ao = (f32x4){0.0f, 0.0f, 0.0f, 0.0f};
#pragma unroll
    for (int ks = 0; ks < 8; ++ks){
      const int kc = ks * 32 + lg * 8;
      f16x8 va = LDW(&Ah0[ACOL(wv * 16 + l15, kc)]);
      f16x8 vl = LDW(&Al0[ACOL(wv * 16 + l15, kc)]);
      f16x8 vb = LDW(&WoT[(ks * 64 + lane) * 8]);
      ao = __builtin_amdgcn_mfma_f32_16x16x32_f16(va, vb, ao, 0, 0, 0);
      ao = __builtin_amdgcn_mfma_f32_16x16x32_f16(vl, vb, ao, 0, 0, 0);
    }
    if (l15 < 3){
      const float bo = bout[l15];
#pragma unroll
      for (int rg2 = 0; rg2 < 4; ++rg2){
        const int row = wv * 16 + lg * 4 + rg2;
        out[((size_t)bi * 16384 + n0 + row) * 3 + l15] = fast_tanh(ao[rg2] + bo);
      }
    }
  }
}

// ------------------------------- launch --------------------------------------
extern "C" void kernel_launch(void* const* d_in, const int* in_sizes, int n_in,
                              void* d_out, int out_size, void* d_ws, size_t ws_size,
                              hipStream_t stream){
  (void)in_sizes; (void)n_in; (void)out_size;
  const float* fg     = (const float*)d_in[0];
  const float* cv     = (const float*)d_in[1];
  const float* coords = (const float*)d_in[2];
  const float* Wc     = (const float*)d_in[3];
  const float* bc     = (const float*)d_in[4];
  const float* W0     = (const float*)d_in[5];
  const float* b0     = (const float*)d_in[6];
  const float* W1     = (const float*)d_in[7];
  const float* b1     = (const float*)d_in[8];
  const float* W2     = (const float*)d_in[9];
  const float* b2     = (const float*)d_in[10];
  const float* W3     = (const float*)d_in[11];
  const float* b3     = (const float*)d_in[12];
  const float* Wout   = (const float*)d_in[13];
  const float* bout   = (const float*)d_in[14];

  char* ws = (char*)d_ws;
  float*          p1    = (float*)(ws);                    // 8*32*32*64 f32 = 2 MB
  float*          p2    = (float*)(ws + 2097152);          // 8*16*16*64 f32 = 512 KB
  unsigned short* WTh   = (unsigned short*)(ws + 2621440); // 4*256*256 f16 = 512 KB
  unsigned short* WTl   = (unsigned short*)(ws + 3145728); // 512 KB (unused)
  unsigned short* WoT   = (unsigned short*)(ws + 3670016); // 8*64*8 f16
  float*          gam   = (float*)(ws + 3678208);          // 8*256 f32
  float*          bet   = (float*)(ws + 3686400);          // 8*256 f32
  // PE tables (optional, 2 x 1.5 MB)
  const size_t PEH_OFF = 4194304, PEL_OFF = 5767168, PE_END = 7340032;
  bool use_pe = (ws_size >= PE_END);
  unsigned short* PEh = use_pe ? (unsigned short*)(ws + PEH_OFF) : nullptr;
  unsigned short* PEl = use_pe ? (unsigned short*)(ws + PEL_OFF) : nullptr;
  float* outp = (float*)d_out;

  pyr_kernel<<<dim3(2048), dim3(256), 0, stream>>>(fg, p1, 32, 32, 2.0f);
  pyr_kernel<<<dim3(512),  dim3(256), 0, stream>>>(fg, p2, 16, 16, 4.0f);
  prep_wt  <<<dim3(1024),  dim3(256), 0, stream>>>(W0, W1, W2, W3, WTh, WTl);
  prep_misc<<<dim3(32),    dim3(256), 0, stream>>>(cv, Wc, bc, Wout, gam, bet, WoT);
  if (use_pe)
    pe_kernel<<<dim3(768), dim3(256), 0, stream>>>(coords, PEh, PEl);
  dec_main <<<dim3(2048),  dim3(512), 0, stream>>>(fg, coords, p1, p2, WTh, WTl, WoT,
                                                   PEh, PEl,
                                                   gam, bet, b0, b1, b2, b3, bout, outp);
}

// Round 16
// 243.992 us; speedup vs baseline: 1.3475x; 1.0560x over previous
//
#include <hip/hip_runtime.h>
#include <math.h>

typedef _Float16 f16x8 __attribute__((ext_vector_type(8)));
typedef float f32x4 __attribute__((ext_vector_type(4)));
typedef float f32x16 __attribute__((ext_vector_type(16)));
typedef unsigned short us8 __attribute__((ext_vector_type(8)));
typedef unsigned short us4 __attribute__((ext_vector_type(4)));

#define PI_F 3.14159265358979323846f

__device__ __forceinline__ void split16(float f, unsigned short& h, unsigned short& l){
  _Float16 hi = (_Float16)f;
  _Float16 lo = (_Float16)(f - (float)hi);
  h = __builtin_bit_cast(unsigned short, hi);
  l = __builtin_bit_cast(unsigned short, lo);
}

__device__ __forceinline__ float fast_gelu(float v){
  float u2 = v * v;
  float z  = v * fmaf(u2, 0.03567740814f, 0.7978845608f);
  float e  = __builtin_amdgcn_exp2f(z * 2.885390082f);   // 2*log2(e)
  float r  = __builtin_amdgcn_rcpf(e + 1.0f);
  return v - v * r;
}

__device__ __forceinline__ float fast_tanh(float v){
  float e = __builtin_amdgcn_exp2f(v * 2.885390082f);
  float r = __builtin_amdgcn_rcpf(e + 1.0f);
  return 1.0f - 2.0f * r;
}

// LDS tile addressing in ushort units, XOR swizzle for bank balance
#define ACOL(rr,cc) (((rr) << 8) + ((cc) ^ ((((rr) & 15)) << 3)))

#define LDW(ptr) __builtin_bit_cast(f16x8, *reinterpret_cast<const us8*>(ptr))

// ---------------- pyramid (jax.image.resize bilinear, antialias=True) -------
__global__ void pyr_kernel(const float* __restrict__ fg, float* __restrict__ out,
                           int Ho, int Wo, float inv_scale){
  int idx = blockIdx.x * blockDim.x + threadIdx.x;
  int total = 8 * Ho * Wo * 64;
  if (idx >= total) return;
  int c  = idx & 63;
  int xy = idx >> 6;
  int x  = xy % Wo;
  int y  = (xy / Wo) % Ho;
  int b  = xy / (Wo * Ho);
  float cyc = inv_scale * (y + 0.5f) - 0.5f;
  float cxc = inv_scale * (x + 0.5f) - 0.5f;
  int iy0 = (int)ceilf(cyc - inv_scale); if (iy0 < 0) iy0 = 0;
  int iy1 = (int)floorf(cyc + inv_scale); if (iy1 > 63) iy1 = 63;
  int ix0 = (int)ceilf(cxc - inv_scale); if (ix0 < 0) ix0 = 0;
  int ix1 = (int)floorf(cxc + inv_scale); if (ix1 > 63) ix1 = 63;
  float rinv = 1.0f / inv_scale;
  float wxs = 0.0f;
  for (int ix = ix0; ix <= ix1; ++ix){
    float w = 1.0f - fabsf(ix - cxc) * rinv;
    if (w > 0.0f) wxs += w;
  }
  float wys = 0.0f, acc = 0.0f;
  for (int iy = iy0; iy <= iy1; ++iy){
    float wy = 1.0f - fabsf(iy - cyc) * rinv;
    if (wy <= 0.0f) continue;
    wys += wy;
    const float* rowp = fg + (((b * 64) + iy) * 64) * 64 + c;
    for (int ix = ix0; ix <= ix1; ++ix){
      float wx = 1.0f - fabsf(ix - cxc) * rinv;
      if (wx <= 0.0f) continue;
      acc += wy * wx * rowp[ix * 64];
    }
  }
  out[idx] = acc / (wys * wxs);
}

// ------------- posenc table: PE[n][48] split f16 (shared across images) -----
__global__ void pe_kernel(const float* __restrict__ coords,
                          unsigned short* __restrict__ peh,
                          unsigned short* __restrict__ pel){
  int idx = blockIdx.x * 256 + threadIdx.x;   // < 196608
  if (idx >= 16384 * 12) return;
  int n = idx / 12, slot = idx % 12;
  const float cy = coords[2 * n], cx = coords[2 * n + 1];
  unsigned short h, l;
  if (slot == 0){
    split16(cy, h, l); peh[n * 48 + 0] = h; pel[n * 48 + 0] = l;
    split16(cx, h, l); peh[n * 48 + 1] = h; pel[n * 48 + 1] = l;
  } else if (slot <= 10){
    int i = slot - 1;
    float f = PI_F * (float)(1 << i);
    float sy, cyv, sx, cxv;
    sincosf(cy * f, &sy, &cyv);
    sincosf(cx * f, &sx, &cxv);
    split16(sy,  h, l); peh[n * 48 + 2 + 4 * i] = h; pel[n * 48 + 2 + 4 * i] = l;
    split16(sx,  h, l); peh[n * 48 + 3 + 4 * i] = h; pel[n * 48 + 3 + 4 * i] = l;
    split16(cyv, h, l); peh[n * 48 + 4 + 4 * i] = h; pel[n * 48 + 4 + 4 * i] = l;
    split16(cxv, h, l); peh[n * 48 + 5 + 4 * i] = h; pel[n * 48 + 5 + 4 * i] = l;
  } else {
#pragma unroll
    for (int j = 42; j < 48; ++j){ peh[n * 48 + j] = 0; pel[n * 48 + j] = 0; }
  }
}

// ------------- weight prep: pre-tiled per-lane 32x32x16 MFMA fragments ------
// WT[l][cfg][ks][lane][e]: col = cfg*32 + (lane&31), k = ks*16 + (lane>>5)*8 + e
// layer0 k-remap: k<42 -> W0 row k; 42..47 pad; 48..239 -> row k-6; 240..255 pad
__global__ void prep_wt(const float* __restrict__ W0, const float* __restrict__ W1,
                        const float* __restrict__ W2, const float* __restrict__ W3,
                        unsigned short* __restrict__ WTh, unsigned short* __restrict__ WTl){
  int idx = blockIdx.x * 256 + threadIdx.x;      // < 262144
  int l    = idx >> 16;
  int rem  = idx & 65535;
  int cfg  = rem >> 13;          // 0..7
  int ks   = (rem >> 9) & 15;    // 0..15
  int lane = (rem >> 3) & 63;
  int e    = idx & 7;
  int col  = cfg * 32 + (lane & 31);
  int k    = ks * 16 + (lane >> 5) * 8 + e;
  float v;
  if (l == 0){
    int row; bool valid;
    if (k < 42)                 { row = k;     valid = true; }
    else if (k >= 48 && k < 240){ row = k - 6; valid = true; }
    else                        { row = 0;     valid = false; }
    v = valid ? W0[row * 256 + col] : 0.0f;
  } else {
    const float* W = (l == 1) ? W1 : ((l == 2) ? W2 : W3);
    v = W[k * 256 + col];
  }
  unsigned short h, lo;
  split16(v, h, lo);
  WTh[idx] = h;
  WTl[idx] = lo;    // unused (weights f16-only) — kept for layout stability
}

// ------------- FiLM params + Wout tiled fragments (16x16 head) --------------
__global__ void prep_misc(const float* __restrict__ cv, const float* __restrict__ Wc,
                          const float* __restrict__ bc, const float* __restrict__ Wout,
                          float* __restrict__ gamma, float* __restrict__ beta,
                          unsigned short* __restrict__ WoT){
  int idx = blockIdx.x * 256 + threadIdx.x;      // < 8192
  if (idx < 4096){
    int b = idx >> 9, j = idx & 511;
    float a = bc[j];
    for (int c = 0; c < 64; ++c) a += cv[b * 64 + c] * Wc[c * 512 + j];
    if (j < 256) gamma[b * 256 + j] = a + 1.0f;
    else         beta[b * 256 + (j - 256)] = a;
  } else {
    int j = idx - 4096;                // WoT[ks][lane][e]
    int ks = j >> 9, lane = (j >> 3) & 63, e = j & 7;
    int col = lane & 15;
    int k = ks * 32 + (lane >> 4) * 8 + e;
    float v = (col < 3) ? Wout[k * 3 + col] : 0.0f;
    _Float16 h = (_Float16)v;
    WoT[j] = __builtin_bit_cast(unsigned short, h);
  }
}

// ------------------------------- main ---------------------------------------
// R15 structure (dbuf tiles, PE table, one barrier/layer) with MFMA operands
// SWAPPED: weights as operand-1, activations as operand-2. By the R14-validated
// black-box relation D(reg,lane) = sum_k X[q(reg,lane),k]*Y[p(lane),k]
// (p=lane&31, q=(reg&3)+8*(reg>>2)+4*(lane>>5)), D-lane is now the activation
// row (fixed per lane) and D-reg the weight column: each reg-quad holds 4
// CONSECUTIVE output cols at one row -> vectorized ds_write_b64 epilogue
// (16 b64 vs 64 b16 per thread/layer) and 4x less address VALU.
// FiLM folded to acc*gm + c2 (c2 = bs*gm+bt) via float4 broadcast LDS loads.
__global__ __launch_bounds__(512, 2)
void dec_main(const float* __restrict__ fg, const float* __restrict__ coords,
              const float* __restrict__ p1, const float* __restrict__ p2,
              const unsigned short* __restrict__ WTh, const unsigned short* __restrict__ WTl,
              const unsigned short* __restrict__ WoT,
              const unsigned short* __restrict__ peh, const unsigned short* __restrict__ pel,
              const float* __restrict__ gamma, const float* __restrict__ beta,
              const float* __restrict__ b0, const float* __restrict__ b1,
              const float* __restrict__ b2, const float* __restrict__ b3,
              const float* __restrict__ bout, float* __restrict__ out){
  __shared__ __align__(16) unsigned short Ah0[64 * 256];  // 32 KB  T0 hi
  __shared__ __align__(16) unsigned short Al0[64 * 256];  // 32 KB  T0 lo
  __shared__ __align__(16) unsigned short Ah1[64 * 256];  // 32 KB  T1 hi
  __shared__ __align__(16) unsigned short Al1[64 * 256];  // 32 KB  T1 lo
  __shared__ __align__(16) float Pgs[256];                // gamma
  __shared__ __align__(16) float C2s[4][256];             // bs*gm + bt per layer

  const int t  = threadIdx.x;
  const int bi = blockIdx.x >> 8;           // image 0..7   (R4-validated decode)
  const int n0 = (blockIdx.x & 255) * 64;   // first coord row of this block

  const int lane = t & 63;
  const int wv   = t >> 6;         // 0..7
  const int l15  = lane & 15;      // head (16x16) lane decode
  const int lg   = lane >> 4;
  const int l31  = lane & 31;      // 32x32 lane decode
  const int lhi  = lane >> 5;      // 0/1

  const int rg   = wv >> 2;        // row group 0/1  -> rows rg*32..+32
  const int cg   = wv & 3;         // col group 0..3 -> cols cg*64..+64
  const int arow = rg * 32 + l31;  // this lane's activation row

  // ---------------- phase 0: params + features into T0 ---------------------
  if (t < 256){
    // FiLM param staging: Pgs = gamma, C2s[l] = b_l*gm + bt
    const float gm = gamma[bi * 256 + t];
    const float bt = beta[bi * 256 + t];
    Pgs[t] = gm;
    C2s[0][t] = fmaf(b0[t], gm, bt);
    C2s[1][t] = fmaf(b1[t], gm, bt);
    C2s[2][t] = fmaf(b2[t], gm, bt);
    C2s[3][t] = fmaf(b3[t], gm, bt);

    const int r = t >> 2, q = t & 3;
    const int n = n0 + r;
    const float cy = coords[2 * n], cx = coords[2 * n + 1];

    if (q == 0){
      if (peh){
        const unsigned short* ph = peh + (size_t)n * 48;
        const unsigned short* pl = pel + (size_t)n * 48;
#pragma unroll
        for (int u = 0; u < 6; ++u){
          us8 vh = *reinterpret_cast<const us8*>(ph + u * 8);
          us8 vl = *reinterpret_cast<const us8*>(pl + u * 8);
          *reinterpret_cast<us8*>(&Ah0[ACOL(r, u * 8)]) = vh;
          *reinterpret_cast<us8*>(&Al0[ACOL(r, u * 8)]) = vl;
        }
      } else {
        float e[48];
        e[0] = cy; e[1] = cx;
#pragma unroll
        for (int i = 0; i < 10; ++i){
          float f = PI_F * (float)(1 << i);
          float sy, cyv, sx, cxv;
          sincosf(cy * f, &sy, &cyv);
          sincosf(cx * f, &sx, &cxv);
          e[2 + 4 * i] = sy;
          e[3 + 4 * i] = sx;
          e[4 + 4 * i] = cyv;
          e[5 + 4 * i] = cxv;
        }
#pragma unroll
        for (int j = 42; j < 48; ++j) e[j] = 0.0f;
#pragma unroll
        for (int u = 0; u < 6; ++u){
          us8 vh, vl;
#pragma unroll
          for (int j = 0; j < 8; ++j){
            unsigned short h, l;
            split16(e[8 * u + j], h, l);
            vh[j] = h; vl[j] = l;
          }
          *reinterpret_cast<us8*>(&Ah0[ACOL(r, u * 8)]) = vh;
          *reinterpret_cast<us8*>(&Al0[ACOL(r, u * 8)]) = vl;
        }
      }
    }
    if (q == 1){   // zero pad cols 240..255
      us8 z = {0,0,0,0,0,0,0,0};
      *reinterpret_cast<us8*>(&Ah0[ACOL(r, 240)]) = z;
      *reinterpret_cast<us8*>(&Ah0[ACOL(r, 248)]) = z;
      *reinterpret_cast<us8*>(&Al0[ACOL(r, 240)]) = z;
      *reinterpret_cast<us8*>(&Al0[ACOL(r, 248)]) = z;
    }

    // bilinear sample 16 channels per thread from each pyramid level
#pragma unroll
    for (int L = 0; L < 3; ++L){
      const int HL = 64 >> L;
      const float* g = (L == 0) ? fg : ((L == 1) ? p1 : p2);
      float yy = (cy + 1.0f) * 0.5f * (HL - 1);
      float xx = (cx + 1.0f) * 0.5f * (HL - 1);
      float y0f = floorf(yy), x0f = floorf(xx);
      float wy = yy - y0f, wx = xx - x0f;
      int y0 = (int)y0f, x0 = (int)x0f;
      y0 = min(max(y0, 0), HL - 1); x0 = min(max(x0, 0), HL - 1);
      int y1 = min(y0 + 1, HL - 1), x1 = min(x0 + 1, HL - 1);
      const int c0 = q * 16;
      const float* g00 = g + (((bi * HL + y0) * HL) + x0) * 64 + c0;
      const float* g01 = g + (((bi * HL + y0) * HL) + x1) * 64 + c0;
      const float* g10 = g + (((bi * HL + y1) * HL) + x0) * 64 + c0;
      const float* g11 = g + (((bi * HL + y1) * HL) + x1) * 64 + c0;
      float w00 = (1 - wy) * (1 - wx), w01 = (1 - wy) * wx;
      float w10 = wy * (1 - wx),       w11 = wy * wx;
      float o[16];
#pragma unroll
      for (int u = 0; u < 4; ++u){
        float4 v0 = *reinterpret_cast<const float4*>(g00 + 4 * u);
        float4 v1 = *reinterpret_cast<const float4*>(g01 + 4 * u);
        float4 v2 = *reinterpret_cast<const float4*>(g10 + 4 * u);
        float4 v3 = *reinterpret_cast<const float4*>(g11 + 4 * u);
        o[4*u+0] = w00*v0.x + w01*v1.x + w10*v2.x + w11*v3.x;
        o[4*u+1] = w00*v0.y + w01*v1.y + w10*v2.y + w11*v3.y;
        o[4*u+2] = w00*v0.z + w01*v1.z + w10*v2.z + w11*v3.z;
        o[4*u+3] = w00*v0.w + w01*v1.w + w10*v2.w + w11*v3.w;
      }
      us8 h0, h1, l0, l1;
#pragma unroll
      for (int j = 0; j < 8; ++j){
        unsigned short h, l;
        split16(o[j], h, l);      h0[j] = h; l0[j] = l;
        split16(o[8 + j], h, l);  h1[j] = h; l1[j] = l;
      }
      const int colb = 48 + 64 * L + 16 * q;
      *reinterpret_cast<us8*>(&Ah0[ACOL(r, colb)])     = h0;
      *reinterpret_cast<us8*>(&Ah0[ACOL(r, colb + 8)]) = h1;
      *reinterpret_cast<us8*>(&Al0[ACOL(r, colb)])     = l0;
      *reinterpret_cast<us8*>(&Al0[ACOL(r, colb + 8)]) = l1;
    }
  }
  __syncthreads();

  // ---------------- phase 1: 4 FiLM-gelu MLP layers (32x32x16, swapped) ----
  // Double-buffered: layer l reads T[l&1], writes T[1^(l&1)]; ONE barrier.
  const int b0off = (cg * 2)     * 8192 + lane * 8;
  const int b1off = (cg * 2 + 1) * 8192 + lane * 8;

#pragma unroll
  for (int l = 0; l < 4; ++l){
    const unsigned short* Rh = (l & 1) ? Ah1 : Ah0;   // read tile
    const unsigned short* Rl = (l & 1) ? Al1 : Al0;
    unsigned short*       Wh_t = (l & 1) ? Ah0 : Ah1; // write tile
    unsigned short*       Wl_t = (l & 1) ? Al0 : Al1;

    f32x16 accA, accB;
#pragma unroll
    for (int j = 0; j < 16; ++j){ accA[j] = 0.0f; accB[j] = 0.0f; }

    const unsigned short* Wh = WTh + l * 65536;

    f16x8 bf0[2], bf1[2];
    bf0[0] = LDW(Wh + b0off);
    bf1[0] = LDW(Wh + b1off);

#pragma unroll
    for (int ks = 0; ks < 16; ++ks){
      const int cur = ks & 1, nxt = cur ^ 1;
      if (ks < 15){
        bf0[nxt] = LDW(Wh + b0off + (ks + 1) * 512);
        bf1[nxt] = LDW(Wh + b1off + (ks + 1) * 512);
      }
      const int kc = ks * 16 + lhi * 8;
      f16x8 ah = LDW(&Rh[ACOL(arow, kc)]);
      f16x8 al = LDW(&Rl[ACOL(arow, kc)]);
      // SWAPPED: weights first (-> D reg index = weight col),
      // activations second (-> D lane index = activation row)
      accA = __builtin_amdgcn_mfma_f32_32x32x16_f16(bf0[cur], ah, accA, 0, 0, 0);
      accB = __builtin_amdgcn_mfma_f32_32x32x16_f16(bf1[cur], ah, accB, 0, 0, 0);
      accA = __builtin_amdgcn_mfma_f32_32x32x16_f16(bf0[cur], al, accA, 0, 0, 0);
      accB = __builtin_amdgcn_mfma_f32_32x32x16_f16(bf1[cur], al, accB, 0, 0, 0);
    }
    // no barrier here: epilogue writes the OTHER tile (disjoint).

    // epilogue: reg-quad g covers cols colb..colb+3 at row arow
#define EPI32(ACC, CF) do { \
      _Pragma("unroll") \
      for (int g = 0; g < 4; ++g){ \
        const int colb = cg * 64 + (CF) * 32 + 4 * lhi + 8 * g; \
        const float4 gm4 = *reinterpret_cast<const float4*>(&Pgs[colb]); \
        const float4 c24 = *reinterpret_cast<const float4*>(&C2s[l][colb]); \
        us4 hh, ll; \
        { float v = fmaf((ACC)[4*g+0], gm4.x, c24.x); float gg = fast_gelu(v); \
          unsigned short h_, l_; split16(gg, h_, l_); hh[0]=h_; ll[0]=l_; } \
        { float v = fmaf((ACC)[4*g+1], gm4.y, c24.y); float gg = fast_gelu(v); \
          unsigned short h_, l_; split16(gg, h_, l_); hh[1]=h_; ll[1]=l_; } \
        { float v = fmaf((ACC)[4*g+2], gm4.z, c24.z); float gg = fast_gelu(v); \
          unsigned short h_, l_; split16(gg, h_, l_); hh[2]=h_; ll[2]=l_; } \
        { float v = fmaf((ACC)[4*g+3], gm4.w, c24.w); float gg = fast_gelu(v); \
          unsigned short h_, l_; split16(gg, h_, l_); hh[3]=h_; ll[3]=l_; } \
        *reinterpret_cast<us4*>(&Wh_t[ACOL(arow, colb)]) = hh; \
        *reinterpret_cast<us4*>(&Wl_t[ACOL(arow, colb)]) = ll; \
      } } while(0)
    EPI32(accA, 0);
    EPI32(accB, 1);
#undef EPI32
    __syncthreads();   // writes to T[next] visible before next layer reads it
  }

  // ---------------- phase 2: output head (256 -> 3) + tanh (16x16 path) ----
  // Final activations in T0 (l=3 wrote T0).
  if (wv < 4){
    f32x4 ao = (f32x4){0.0f, 0.0f, 0.0f, 0.0f};
#pragma unroll
    for (int ks = 0; ks < 8; ++ks){
      const int kc = ks * 32 + lg * 8;
      f16x8 va = LDW(&Ah0[ACOL(wv * 16 + l15, kc)]);
      f16x8 vl = LDW(&Al0[ACOL(wv * 16 + l15, kc)]);
      f16x8 vb = LDW(&WoT[(ks * 64 + lane) * 8]);
      ao = __builtin_amdgcn_mfma_f32_16x16x32_f16(va, vb, ao, 0, 0, 0);
      ao = __builtin_amdgcn_mfma_f32_16x16x32_f16(vl, vb, ao, 0, 0, 0);
    }
    if (l15 < 3){
      const float bo = bout[l15];
#pragma unroll
      for (int rg2 = 0; rg2 < 4; ++rg2){
        const int row = wv * 16 + lg * 4 + rg2;
        out[((size_t)bi * 16384 + n0 + row) * 3 + l15] = fast_tanh(ao[rg2] + bo);
      }
    }
  }
}

// ------------------------------- launch --------------------------------------
extern "C" void kernel_launch(void* const* d_in, const int* in_sizes, int n_in,
                              void* d_out, int out_size, void* d_ws, size_t ws_size,
                              hipStream_t stream){
  (void)in_sizes; (void)n_in; (void)out_size;
  const float* fg     = (const float*)d_in[0];
  const float* cv     = (const float*)d_in[1];
  const float* coords = (const float*)d_in[2];
  const float* Wc     = (const float*)d_in[3];
  const float* bc     = (const float*)d_in[4];
  const float* W0     = (const float*)d_in[5];
  const float* b0     = (const float*)d_in[6];
  const float* W1     = (const float*)d_in[7];
  const float* b1     = (const float*)d_in[8];
  const float* W2     = (const float*)d_in[9];
  const float* b2     = (const float*)d_in[10];
  const float* W3     = (const float*)d_in[11];
  const float* b3     = (const float*)d_in[12];
  const float* Wout   = (const float*)d_in[13];
  const float* bout   = (const float*)d_in[14];

  char* ws = (char*)d_ws;
  float*          p1    = (float*)(ws);                    // 8*32*32*64 f32 = 2 MB
  float*          p2    = (float*)(ws + 2097152);          // 8*16*16*64 f32 = 512 KB
  unsigned short* WTh   = (unsigned short*)(ws + 2621440); // 4*256*256 f16 = 512 KB
  unsigned short* WTl   = (unsigned short*)(ws + 3145728); // 512 KB (unused)
  unsigned short* WoT   = (unsigned short*)(ws + 3670016); // 8*64*8 f16
  float*          gam   = (float*)(ws + 3678208);          // 8*256 f32
  float*          bet   = (float*)(ws + 3686400);          // 8*256 f32
  // PE tables (optional, 2 x 1.5 MB)
  const size_t PEH_OFF = 4194304, PEL_OFF = 5767168, PE_END = 7340032;
  bool use_pe = (ws_size >= PE_END);
  unsigned short* PEh = use_pe ? (unsigned short*)(ws + PEH_OFF) : nullptr;
  unsigned short* PEl = use_pe ? (unsigned short*)(ws + PEL_OFF) : nullptr;
  float* outp = (float*)d_out;

  pyr_kernel<<<dim3(2048), dim3(256), 0, stream>>>(fg, p1, 32, 32, 2.0f);
  pyr_kernel<<<dim3(512),  dim3(256), 0, stream>>>(fg, p2, 16, 16, 4.0f);
  prep_wt  <<<dim3(1024),  dim3(256), 0, stream>>>(W0, W1, W2, W3, WTh, WTl);
  prep_misc<<<dim3(32),    dim3(256), 0, stream>>>(cv, Wc, bc, Wout, gam, bet, WoT);
  if (use_pe)
    pe_kernel<<<dim3(768), dim3(256), 0, stream>>>(coords, PEh, PEl);
  dec_main <<<dim3(2048),  dim3(512), 0, stream>>>(fg, coords, p1, p2, WTh, WTl, WoT,
                                                   PEh, PEl,
                                                   gam, bet, b0, b1, b2, b3, bout, outp);
}

// Round 17
// 197.386 us; speedup vs baseline: 1.6657x; 1.2361x over previous
//
#include <hip/hip_runtime.h>
#include <math.h>

typedef _Float16 f16x8 __attribute__((ext_vector_type(8)));
typedef float f32x4 __attribute__((ext_vector_type(4)));
typedef float f32x16 __attribute__((ext_vector_type(16)));
typedef unsigned short us8 __attribute__((ext_vector_type(8)));
typedef unsigned short us4 __attribute__((ext_vector_type(4)));

#define PI_F 3.14159265358979323846f

__device__ __forceinline__ void split16(float f, unsigned short& h, unsigned short& l){
  _Float16 hi = (_Float16)f;
  _Float16 lo = (_Float16)(f - (float)hi);
  h = __builtin_bit_cast(unsigned short, hi);
  l = __builtin_bit_cast(unsigned short, lo);
}

__device__ __forceinline__ unsigned short f2h(float f){
  _Float16 hi = (_Float16)f;
  return __builtin_bit_cast(unsigned short, hi);
}

__device__ __forceinline__ float fast_gelu(float v){
  float u2 = v * v;
  float z  = v * fmaf(u2, 0.03567740814f, 0.7978845608f);
  float e  = __builtin_amdgcn_exp2f(z * 2.885390082f);   // 2*log2(e)
  float r  = __builtin_amdgcn_rcpf(e + 1.0f);
  return v - v * r;
}

__device__ __forceinline__ float fast_tanh(float v){
  float e = __builtin_amdgcn_exp2f(v * 2.885390082f);
  float r = __builtin_amdgcn_rcpf(e + 1.0f);
  return 1.0f - 2.0f * r;
}

// LDS tile addressing in ushort units, XOR swizzle for bank balance
#define ACOL(rr,cc) (((rr) << 8) + ((cc) ^ ((((rr) & 15)) << 3)))

#define LDW(ptr) __builtin_bit_cast(f16x8, *reinterpret_cast<const us8*>(ptr))

// ---------------- pyramid (jax.image.resize bilinear, antialias=True) -------
__global__ void pyr_kernel(const float* __restrict__ fg, float* __restrict__ out,
                           int Ho, int Wo, float inv_scale){
  int idx = blockIdx.x * blockDim.x + threadIdx.x;
  int total = 8 * Ho * Wo * 64;
  if (idx >= total) return;
  int c  = idx & 63;
  int xy = idx >> 6;
  int x  = xy % Wo;
  int y  = (xy / Wo) % Ho;
  int b  = xy / (Wo * Ho);
  float cyc = inv_scale * (y + 0.5f) - 0.5f;
  float cxc = inv_scale * (x + 0.5f) - 0.5f;
  int iy0 = (int)ceilf(cyc - inv_scale); if (iy0 < 0) iy0 = 0;
  int iy1 = (int)floorf(cyc + inv_scale); if (iy1 > 63) iy1 = 63;
  int ix0 = (int)ceilf(cxc - inv_scale); if (ix0 < 0) ix0 = 0;
  int ix1 = (int)floorf(cxc + inv_scale); if (ix1 > 63) ix1 = 63;
  float rinv = 1.0f / inv_scale;
  float wxs = 0.0f;
  for (int ix = ix0; ix <= ix1; ++ix){
    float w = 1.0f - fabsf(ix - cxc) * rinv;
    if (w > 0.0f) wxs += w;
  }
  float wys = 0.0f, acc = 0.0f;
  for (int iy = iy0; iy <= iy1; ++iy){
    float wy = 1.0f - fabsf(iy - cyc) * rinv;
    if (wy <= 0.0f) continue;
    wys += wy;
    const float* rowp = fg + (((b * 64) + iy) * 64) * 64 + c;
    for (int ix = ix0; ix <= ix1; ++ix){
      float wx = 1.0f - fabsf(ix - cxc) * rinv;
      if (wx <= 0.0f) continue;
      acc += wy * wx * rowp[ix * 64];
    }
  }
  out[idx] = acc / (wys * wxs);
}

// ------------- posenc table: PE[n][48] f16 (shared across images) -----------
__global__ void pe_kernel(const float* __restrict__ coords,
                          unsigned short* __restrict__ peh){
  int idx = blockIdx.x * 256 + threadIdx.x;   // < 196608
  if (idx >= 16384 * 12) return;
  int n = idx / 12, slot = idx % 12;
  const float cy = coords[2 * n], cx = coords[2 * n + 1];
  if (slot == 0){
    peh[n * 48 + 0] = f2h(cy);
    peh[n * 48 + 1] = f2h(cx);
  } else if (slot <= 10){
    int i = slot - 1;
    float f = PI_F * (float)(1 << i);
    float sy, cyv, sx, cxv;
    sincosf(cy * f, &sy, &cyv);
    sincosf(cx * f, &sx, &cxv);
    peh[n * 48 + 2 + 4 * i] = f2h(sy);
    peh[n * 48 + 3 + 4 * i] = f2h(sx);
    peh[n * 48 + 4 + 4 * i] = f2h(cyv);
    peh[n * 48 + 5 + 4 * i] = f2h(cxv);
  } else {
#pragma unroll
    for (int j = 42; j < 48; ++j) peh[n * 48 + j] = 0;
  }
}

// ------------- weight prep: pre-tiled per-lane 32x32x16 MFMA fragments ------
// WT[l][cfg][ks][lane][e]: col = cfg*32 + (lane&31), k = ks*16 + (lane>>5)*8 + e
// layer0 k-remap: k<42 -> W0 row k; 42..47 pad; 48..239 -> row k-6; 240..255 pad
__global__ void prep_wt(const float* __restrict__ W0, const float* __restrict__ W1,
                        const float* __restrict__ W2, const float* __restrict__ W3,
                        unsigned short* __restrict__ WTh){
  int idx = blockIdx.x * 256 + threadIdx.x;      // < 262144
  int l    = idx >> 16;
  int rem  = idx & 65535;
  int cfg  = rem >> 13;          // 0..7
  int ks   = (rem >> 9) & 15;    // 0..15
  int lane = (rem >> 3) & 63;
  int e    = idx & 7;
  int col  = cfg * 32 + (lane & 31);
  int k    = ks * 16 + (lane >> 5) * 8 + e;
  float v;
  if (l == 0){
    int row; bool valid;
    if (k < 42)                 { row = k;     valid = true; }
    else if (k >= 48 && k < 240){ row = k - 6; valid = true; }
    else                        { row = 0;     valid = false; }
    v = valid ? W0[row * 256 + col] : 0.0f;
  } else {
    const float* W = (l == 1) ? W1 : ((l == 2) ? W2 : W3);
    v = W[k * 256 + col];
  }
  WTh[idx] = f2h(v);
}

// ------------- FiLM params + Wout tiled fragments (16x16 head) --------------
__global__ void prep_misc(const float* __restrict__ cv, const float* __restrict__ Wc,
                          const float* __restrict__ bc, const float* __restrict__ Wout,
                          float* __restrict__ gamma, float* __restrict__ beta,
                          unsigned short* __restrict__ WoT){
  int idx = blockIdx.x * 256 + threadIdx.x;      // < 8192
  if (idx < 4096){
    int b = idx >> 9, j = idx & 511;
    float a = bc[j];
    for (int c = 0; c < 64; ++c) a += cv[b * 64 + c] * Wc[c * 512 + j];
    if (j < 256) gamma[b * 256 + j] = a + 1.0f;
    else         beta[b * 256 + (j - 256)] = a;
  } else {
    int j = idx - 4096;                // WoT[ks][lane][e]
    int ks = j >> 9, lane = (j >> 3) & 63, e = j & 7;
    int col = lane & 15;
    int k = ks * 32 + (lane >> 4) * 8 + e;
    float v = (col < 3) ? Wout[k * 3 + col] : 0.0f;
    WoT[j] = f2h(v);
  }
}

// ------------------------------- main ---------------------------------------
// R16 structure (swapped operands, dbuf tiles, PE table, one barrier/layer)
// with activations f16-ONLY (Al tiles dropped; R6's first-check absmax 0.0039
// proved act-f16 numerics fine — its :515 failure was the 12-waves/CU config).
// Single MFMA product per B-fragment: halves MFMA work, LDS reads, and
// epilogue stores. Tiles padded to [80*256] (40 KB each) so total LDS = 85 KB
// > 80 KB -> only ONE block/CU can be resident: stays in the proven-safe
// 8-waves/CU regime (>8 waves/CU corrupts: R3/R5/R6/R9/R11).
__global__ __launch_bounds__(512, 2)
void dec_main(const float* __restrict__ fg, const float* __restrict__ coords,
              const float* __restrict__ p1, const float* __restrict__ p2,
              const unsigned short* __restrict__ WTh,
              const unsigned short* __restrict__ WoT,
              const unsigned short* __restrict__ peh,
              const float* __restrict__ gamma, const float* __restrict__ beta,
              const float* __restrict__ b0, const float* __restrict__ b1,
              const float* __restrict__ b2, const float* __restrict__ b3,
              const float* __restrict__ bout, float* __restrict__ out){
  __shared__ __align__(16) unsigned short Ah0[80 * 256];  // 40 KB T0 (rows 0..63 used)
  __shared__ __align__(16) unsigned short Ah1[80 * 256];  // 40 KB T1 (pad -> 1 blk/CU)
  __shared__ __align__(16) float Pgs[256];                // gamma
  __shared__ __align__(16) float C2s[4][256];             // bs*gm + bt per layer

  const int t  = threadIdx.x;
  const int bi = blockIdx.x >> 8;           // image 0..7   (R4-validated decode)
  const int n0 = (blockIdx.x & 255) * 64;   // first coord row of this block

  const int lane = t & 63;
  const int wv   = t >> 6;         // 0..7
  const int l15  = lane & 15;      // head (16x16) lane decode
  const int lg   = lane >> 4;
  const int l31  = lane & 31;      // 32x32 lane decode
  const int lhi  = lane >> 5;      // 0/1

  const int rg   = wv >> 2;        // row group 0/1  -> rows rg*32..+32
  const int cg   = wv & 3;         // col group 0..3 -> cols cg*64..+64
  const int arow = rg * 32 + l31;  // this lane's activation row

  // ---------------- phase 0: params + features into T0 ---------------------
  if (t < 256){
    // FiLM param staging: Pgs = gamma, C2s[l] = b_l*gm + bt
    const float gm = gamma[bi * 256 + t];
    const float bt = beta[bi * 256 + t];
    Pgs[t] = gm;
    C2s[0][t] = fmaf(b0[t], gm, bt);
    C2s[1][t] = fmaf(b1[t], gm, bt);
    C2s[2][t] = fmaf(b2[t], gm, bt);
    C2s[3][t] = fmaf(b3[t], gm, bt);

    const int r = t >> 2, q = t & 3;
    const int n = n0 + r;
    const float cy = coords[2 * n], cx = coords[2 * n + 1];

    if (q == 0){
      if (peh){
        const unsigned short* ph = peh + (size_t)n * 48;
#pragma unroll
        for (int u = 0; u < 6; ++u){
          us8 vh = *reinterpret_cast<const us8*>(ph + u * 8);
          *reinterpret_cast<us8*>(&Ah0[ACOL(r, u * 8)]) = vh;
        }
      } else {
        float e[48];
        e[0] = cy; e[1] = cx;
#pragma unroll
        for (int i = 0; i < 10; ++i){
          float f = PI_F * (float)(1 << i);
          float sy, cyv, sx, cxv;
          sincosf(cy * f, &sy, &cyv);
          sincosf(cx * f, &sx, &cxv);
          e[2 + 4 * i] = sy;
          e[3 + 4 * i] = sx;
          e[4 + 4 * i] = cyv;
          e[5 + 4 * i] = cxv;
        }
#pragma unroll
        for (int j = 42; j < 48; ++j) e[j] = 0.0f;
#pragma unroll
        for (int u = 0; u < 6; ++u){
          us8 vh;
#pragma unroll
          for (int j = 0; j < 8; ++j) vh[j] = f2h(e[8 * u + j]);
          *reinterpret_cast<us8*>(&Ah0[ACOL(r, u * 8)]) = vh;
        }
      }
    }
    if (q == 1){   // zero pad cols 240..255
      us8 z = {0,0,0,0,0,0,0,0};
      *reinterpret_cast<us8*>(&Ah0[ACOL(r, 240)]) = z;
      *reinterpret_cast<us8*>(&Ah0[ACOL(r, 248)]) = z;
    }

    // bilinear sample 16 channels per thread from each pyramid level
#pragma unroll
    for (int L = 0; L < 3; ++L){
      const int HL = 64 >> L;
      const float* g = (L == 0) ? fg : ((L == 1) ? p1 : p2);
      float yy = (cy + 1.0f) * 0.5f * (HL - 1);
      float xx = (cx + 1.0f) * 0.5f * (HL - 1);
      float y0f = floorf(yy), x0f = floorf(xx);
      float wy = yy - y0f, wx = xx - x0f;
      int y0 = (int)y0f, x0 = (int)x0f;
      y0 = min(max(y0, 0), HL - 1); x0 = min(max(x0, 0), HL - 1);
      int y1 = min(y0 + 1, HL - 1), x1 = min(x0 + 1, HL - 1);
      const int c0 = q * 16;
      const float* g00 = g + (((bi * HL + y0) * HL) + x0) * 64 + c0;
      const float* g01 = g + (((bi * HL + y0) * HL) + x1) * 64 + c0;
      const float* g10 = g + (((bi * HL + y1) * HL) + x0) * 64 + c0;
      const float* g11 = g + (((bi * HL + y1) * HL) + x1) * 64 + c0;
      float w00 = (1 - wy) * (1 - wx), w01 = (1 - wy) * wx;
      float w10 = wy * (1 - wx),       w11 = wy * wx;
      float o[16];
#pragma unroll
      for (int u = 0; u < 4; ++u){
        float4 v0 = *reinterpret_cast<const float4*>(g00 + 4 * u);
        float4 v1 = *reinterpret_cast<const float4*>(g01 + 4 * u);
        float4 v2 = *reinterpret_cast<const float4*>(g10 + 4 * u);
        float4 v3 = *reinterpret_cast<const float4*>(g11 + 4 * u);
        o[4*u+0] = w00*v0.x + w01*v1.x + w10*v2.x + w11*v3.x;
        o[4*u+1] = w00*v0.y + w01*v1.y + w10*v2.y + w11*v3.y;
        o[4*u+2] = w00*v0.z + w01*v1.z + w10*v2.z + w11*v3.z;
        o[4*u+3] = w00*v0.w + w01*v1.w + w10*v2.w + w11*v3.w;
      }
      us8 h0, h1;
#pragma unroll
      for (int j = 0; j < 8; ++j){
        h0[j] = f2h(o[j]);
        h1[j] = f2h(o[8 + j]);
      }
      const int colb = 48 + 64 * L + 16 * q;
      *reinterpret_cast<us8*>(&Ah0[ACOL(r, colb)])     = h0;
      *reinterpret_cast<us8*>(&Ah0[ACOL(r, colb + 8)]) = h1;
    }
  }
  __syncthreads();

  // ---------------- phase 1: 4 FiLM-gelu MLP layers (32x32x16, swapped) ----
  // Double-buffered: layer l reads T[l&1], writes T[1^(l&1)]; ONE barrier.
  const int b0off = (cg * 2)     * 8192 + lane * 8;
  const int b1off = (cg * 2 + 1) * 8192 + lane * 8;

#pragma unroll
  for (int l = 0; l < 4; ++l){
    const unsigned short* Rh   = (l & 1) ? Ah1 : Ah0;   // read tile
    unsigned short*       Wh_t = (l & 1) ? Ah0 : Ah1;   // write tile

    f32x16 accA, accB;
#pragma unroll
    for (int j = 0; j < 16; ++j){ accA[j] = 0.0f; accB[j] = 0.0f; }

    const unsigned short* Wh = WTh + l * 65536;

    f16x8 bf0[2], bf1[2];
    bf0[0] = LDW(Wh + b0off);
    bf1[0] = LDW(Wh + b1off);

#pragma unroll
    for (int ks = 0; ks < 16; ++ks){
      const int cur = ks & 1, nxt = cur ^ 1;
      if (ks < 15){
        bf0[nxt] = LDW(Wh + b0off + (ks + 1) * 512);
        bf1[nxt] = LDW(Wh + b1off + (ks + 1) * 512);
      }
      const int kc = ks * 16 + lhi * 8;
      f16x8 ah = LDW(&Rh[ACOL(arow, kc)]);
      // SWAPPED: weights first (-> D reg index = weight col),
      // activations second (-> D lane index = activation row)
      accA = __builtin_amdgcn_mfma_f32_32x32x16_f16(bf0[cur], ah, accA, 0, 0, 0);
      accB = __builtin_amdgcn_mfma_f32_32x32x16_f16(bf1[cur], ah, accB, 0, 0, 0);
    }
    // no barrier here: epilogue writes the OTHER tile (disjoint).

    // epilogue: reg-quad g covers cols colb..colb+3 at row arow
#define EPI32(ACC, CF) do { \
      _Pragma("unroll") \
      for (int g = 0; g < 4; ++g){ \
        const int colb = cg * 64 + (CF) * 32 + 4 * lhi + 8 * g; \
        const float4 gm4 = *reinterpret_cast<const float4*>(&Pgs[colb]); \
        const float4 c24 = *reinterpret_cast<const float4*>(&C2s[l][colb]); \
        us4 hh; \
        { float v = fmaf((ACC)[4*g+0], gm4.x, c24.x); hh[0] = f2h(fast_gelu(v)); } \
        { float v = fmaf((ACC)[4*g+1], gm4.y, c24.y); hh[1] = f2h(fast_gelu(v)); } \
        { float v = fmaf((ACC)[4*g+2], gm4.z, c24.z); hh[2] = f2h(fast_gelu(v)); } \
        { float v = fmaf((ACC)[4*g+3], gm4.w, c24.w); hh[3] = f2h(fast_gelu(v)); } \
        *reinterpret_cast<us4*>(&Wh_t[ACOL(arow, colb)]) = hh; \
      } } while(0)
    EPI32(accA, 0);
    EPI32(accB, 1);
#undef EPI32
    __syncthreads();   // writes to T[next] visible before next layer reads it
  }

  // ---------------- phase 2: output head (256 -> 3) + tanh (16x16 path) ----
  // Final activations in T0 (l=3 wrote T0).
  if (wv < 4){
    f32x4 ao = (f32x4){0.0f, 0.0f, 0.0f, 0.0f};
#pragma unroll
    for (int ks = 0; ks < 8; ++ks){
      const int kc = ks * 32 + lg * 8;
      f16x8 va = LDW(&Ah0[ACOL(wv * 16 + l15, kc)]);
      f16x8 vb = LDW(&WoT[(ks * 64 + lane) * 8]);
      ao = __builtin_amdgcn_mfma_f32_16x16x32_f16(va, vb, ao, 0, 0, 0);
    }
    if (l15 < 3){
      const float bo = bout[l15];
#pragma unroll
      for (int rg2 = 0; rg2 < 4; ++rg2){
        const int row = wv * 16 + lg * 4 + rg2;
        out[((size_t)bi * 16384 + n0 + row) * 3 + l15] = fast_tanh(ao[rg2] + bo);
      }
    }
  }
}

// ------------------------------- launch --------------------------------------
extern "C" void kernel_launch(void* const* d_in, const int* in_sizes, int n_in,
                              void* d_out, int out_size, void* d_ws, size_t ws_size,
                              hipStream_t stream){
  (void)in_sizes; (void)n_in; (void)out_size;
  const float* fg     = (const float*)d_in[0];
  const float* cv     = (const float*)d_in[1];
  const float* coords = (const float*)d_in[2];
  const float* Wc     = (const float*)d_in[3];
  const float* bc     = (const float*)d_in[4];
  const float* W0     = (const float*)d_in[5];
  const float* b0     = (const float*)d_in[6];
  const float* W1     = (const float*)d_in[7];
  const float* b1     = (const float*)d_in[8];
  const float* W2     = (const float*)d_in[9];
  const float* b2     = (const float*)d_in[10];
  const float* W3     = (const float*)d_in[11];
  const float* b3     = (const float*)d_in[12];
  const float* Wout   = (const float*)d_in[13];
  const float* bout   = (const float*)d_in[14];

  char* ws = (char*)d_ws;
  float*          p1    = (float*)(ws);                    // 8*32*32*64 f32 = 2 MB
  float*          p2    = (float*)(ws + 2097152);          // 8*16*16*64 f32 = 512 KB
  unsigned short* WTh   = (unsigned short*)(ws + 2621440); // 4*256*256 f16 = 512 KB
  unsigned short* WoT   = (unsigned short*)(ws + 3670016); // 8*64*8 f16
  float*          gam   = (float*)(ws + 3678208);          // 8*256 f32
  float*          bet   = (float*)(ws + 3686400);          // 8*256 f32
  // PE table (optional, 1.5 MB)
  const size_t PEH_OFF = 4194304, PE_END = 5767168;
  bool use_pe = (ws_size >= PE_END);
  unsigned short* PEh = use_pe ? (unsigned short*)(ws + PEH_OFF) : nullptr;
  float* outp = (float*)d_out;

  pyr_kernel<<<dim3(2048), dim3(256), 0, stream>>>(fg, p1, 32, 32, 2.0f);
  pyr_kernel<<<dim3(512),  dim3(256), 0, stream>>>(fg, p2, 16, 16, 4.0f);
  prep_wt  <<<dim3(1024),  dim3(256), 0, stream>>>(W0, W1, W2, W3, WTh);
  prep_misc<<<dim3(32),    dim3(256), 0, stream>>>(cv, Wc, bc, Wout, gam, bet, WoT);
  if (use_pe)
    pe_kernel<<<dim3(768), dim3(256), 0, stream>>>(coords, PEh);
  dec_main <<<dim3(2048),  dim3(512), 0, stream>>>(fg, coords, p1, p2, WTh, WoT,
                                                   PEh,
                                                   gam, bet, b0, b1, b2, b3, bout, outp);
}

// Round 18
// 186.555 us; speedup vs baseline: 1.7624x; 1.0581x over previous
//
#include <hip/hip_runtime.h>
#include <math.h>

typedef _Float16 f16x8 __attribute__((ext_vector_type(8)));
typedef float f32x4 __attribute__((ext_vector_type(4)));
typedef float f32x16 __attribute__((ext_vector_type(16)));
typedef unsigned short us8 __attribute__((ext_vector_type(8)));
typedef unsigned short us4 __attribute__((ext_vector_type(4)));

#define PI_F 3.14159265358979323846f

__device__ __forceinline__ unsigned short f2h(float f){
  _Float16 hi = (_Float16)f;
  return __builtin_bit_cast(unsigned short, hi);
}

__device__ __forceinline__ float fast_gelu(float v){
  float u2 = v * v;
  float z  = v * fmaf(u2, 0.03567740814f, 0.7978845608f);
  float e  = __builtin_amdgcn_exp2f(z * 2.885390082f);   // 2*log2(e)
  float r  = __builtin_amdgcn_rcpf(e + 1.0f);
  return v - v * r;
}

__device__ __forceinline__ float fast_tanh(float v){
  float e = __builtin_amdgcn_exp2f(v * 2.885390082f);
  float r = __builtin_amdgcn_rcpf(e + 1.0f);
  return 1.0f - 2.0f * r;
}

// LDS tile addressing in ushort units, XOR swizzle for bank balance
#define ACOL(rr,cc) (((rr) << 8) + ((cc) ^ ((((rr) & 15)) << 3)))

#define LDW(ptr) __builtin_bit_cast(f16x8, *reinterpret_cast<const us8*>(ptr))

// ---------------- pyramid (jax.image.resize bilinear, antialias=True) -------
__global__ void pyr_kernel(const float* __restrict__ fg, float* __restrict__ out,
                           int Ho, int Wo, float inv_scale){
  int idx = blockIdx.x * blockDim.x + threadIdx.x;
  int total = 8 * Ho * Wo * 64;
  if (idx >= total) return;
  int c  = idx & 63;
  int xy = idx >> 6;
  int x  = xy % Wo;
  int y  = (xy / Wo) % Ho;
  int b  = xy / (Wo * Ho);
  float cyc = inv_scale * (y + 0.5f) - 0.5f;
  float cxc = inv_scale * (x + 0.5f) - 0.5f;
  int iy0 = (int)ceilf(cyc - inv_scale); if (iy0 < 0) iy0 = 0;
  int iy1 = (int)floorf(cyc + inv_scale); if (iy1 > 63) iy1 = 63;
  int ix0 = (int)ceilf(cxc - inv_scale); if (ix0 < 0) ix0 = 0;
  int ix1 = (int)floorf(cxc + inv_scale); if (ix1 > 63) ix1 = 63;
  float rinv = 1.0f / inv_scale;
  float wxs = 0.0f;
  for (int ix = ix0; ix <= ix1; ++ix){
    float w = 1.0f - fabsf(ix - cxc) * rinv;
    if (w > 0.0f) wxs += w;
  }
  float wys = 0.0f, acc = 0.0f;
  for (int iy = iy0; iy <= iy1; ++iy){
    float wy = 1.0f - fabsf(iy - cyc) * rinv;
    if (wy <= 0.0f) continue;
    wys += wy;
    const float* rowp = fg + (((b * 64) + iy) * 64) * 64 + c;
    for (int ix = ix0; ix <= ix1; ++ix){
      float wx = 1.0f - fabsf(ix - cxc) * rinv;
      if (wx <= 0.0f) continue;
      acc += wy * wx * rowp[ix * 64];
    }
  }
  out[idx] = acc / (wys * wxs);
}

// ------------- posenc table: PE[n][48] f16 (shared across images) -----------
__global__ void pe_kernel(const float* __restrict__ coords,
                          unsigned short* __restrict__ peh){
  int idx = blockIdx.x * 256 + threadIdx.x;   // < 196608
  if (idx >= 16384 * 12) return;
  int n = idx / 12, slot = idx % 12;
  const float cy = coords[2 * n], cx = coords[2 * n + 1];
  if (slot == 0){
    peh[n * 48 + 0] = f2h(cy);
    peh[n * 48 + 1] = f2h(cx);
  } else if (slot <= 10){
    int i = slot - 1;
    float f = PI_F * (float)(1 << i);
    float sy, cyv, sx, cxv;
    sincosf(cy * f, &sy, &cyv);
    sincosf(cx * f, &sx, &cxv);
    peh[n * 48 + 2 + 4 * i] = f2h(sy);
    peh[n * 48 + 3 + 4 * i] = f2h(sx);
    peh[n * 48 + 4 + 4 * i] = f2h(cyv);
    peh[n * 48 + 5 + 4 * i] = f2h(cxv);
  } else {
#pragma unroll
    for (int j = 42; j < 48; ++j) peh[n * 48 + j] = 0;
  }
}

// ------------- weight prep: pre-tiled per-lane 32x32x16 MFMA fragments ------
// WT[l][cfg][ks][lane][e]: col = cfg*32 + (lane&31), k = ks*16 + (lane>>5)*8 + e
// layer0 k-remap: k<42 -> W0 row k; 42..47 pad; 48..239 -> row k-6; 240..255 pad
__global__ void prep_wt(const float* __restrict__ W0, const float* __restrict__ W1,
                        const float* __restrict__ W2, const float* __restrict__ W3,
                        unsigned short* __restrict__ WTh){
  int idx = blockIdx.x * 256 + threadIdx.x;      // < 262144
  int l    = idx >> 16;
  int rem  = idx & 65535;
  int cfg  = rem >> 13;          // 0..7
  int ks   = (rem >> 9) & 15;    // 0..15
  int lane = (rem >> 3) & 63;
  int e    = idx & 7;
  int col  = cfg * 32 + (lane & 31);
  int k    = ks * 16 + (lane >> 5) * 8 + e;
  float v;
  if (l == 0){
    int row; bool valid;
    if (k < 42)                 { row = k;     valid = true; }
    else if (k >= 48 && k < 240){ row = k - 6; valid = true; }
    else                        { row = 0;     valid = false; }
    v = valid ? W0[row * 256 + col] : 0.0f;
  } else {
    const float* W = (l == 1) ? W1 : ((l == 2) ? W2 : W3);
    v = W[k * 256 + col];
  }
  WTh[idx] = f2h(v);
}

// ------------- FiLM params + Wout tiled fragments (16x16 head) --------------
__global__ void prep_misc(const float* __restrict__ cv, const float* __restrict__ Wc,
                          const float* __restrict__ bc, const float* __restrict__ Wout,
                          float* __restrict__ gamma, float* __restrict__ beta,
                          unsigned short* __restrict__ WoT){
  int idx = blockIdx.x * 256 + threadIdx.x;      // < 8192
  if (idx < 4096){
    int b = idx >> 9, j = idx & 511;
    float a = bc[j];
    for (int c = 0; c < 64; ++c) a += cv[b * 64 + c] * Wc[c * 512 + j];
    if (j < 256) gamma[b * 256 + j] = a + 1.0f;
    else         beta[b * 256 + (j - 256)] = a;
  } else {
    int j = idx - 4096;                // WoT[ks][lane][e]
    int ks = j >> 9, lane = (j >> 3) & 63, e = j & 7;
    int col = lane & 15;
    int k = ks * 32 + (lane >> 4) * 8 + e;
    float v = (col < 3) ? Wout[k * 3 + col] : 0.0f;
    WoT[j] = f2h(v);
  }
}

// ------------------------------- main ---------------------------------------
// R17 structure with a depth-8 B-prefetch ring + cross-layer wraparound:
// slots consumed at iter ks are refilled with frag ks+8 (same layer) or, for
// ks>=8, with layer l+1's frag ks-8 — so next layer's prologue loads are in
// flight across the epilogue+barrier and B-loads never stall the K-loop.
// All ring indices are compile-time (both loops fully unrolled).
__global__ __launch_bounds__(512, 2)
void dec_main(const float* __restrict__ fg, const float* __restrict__ coords,
              const float* __restrict__ p1, const float* __restrict__ p2,
              const unsigned short* __restrict__ WTh,
              const unsigned short* __restrict__ WoT,
              const unsigned short* __restrict__ peh,
              const float* __restrict__ gamma, const float* __restrict__ beta,
              const float* __restrict__ b0, const float* __restrict__ b1,
              const float* __restrict__ b2, const float* __restrict__ b3,
              const float* __restrict__ bout, float* __restrict__ out){
  __shared__ __align__(16) unsigned short Ah0[80 * 256];  // 40 KB T0 (rows 0..63 used)
  __shared__ __align__(16) unsigned short Ah1[80 * 256];  // 40 KB T1 (pad -> 1 blk/CU)
  __shared__ __align__(16) float Pgs[256];                // gamma
  __shared__ __align__(16) float C2s[4][256];             // bs*gm + bt per layer

  const int t  = threadIdx.x;
  const int bi = blockIdx.x >> 8;           // image 0..7   (R4-validated decode)
  const int n0 = (blockIdx.x & 255) * 64;   // first coord row of this block

  const int lane = t & 63;
  const int wv   = t >> 6;         // 0..7
  const int l15  = lane & 15;      // head (16x16) lane decode
  const int lg   = lane >> 4;
  const int l31  = lane & 31;      // 32x32 lane decode
  const int lhi  = lane >> 5;      // 0/1

  const int rg   = wv >> 2;        // row group 0/1  -> rows rg*32..+32
  const int cg   = wv & 3;         // col group 0..3 -> cols cg*64..+64
  const int arow = rg * 32 + l31;  // this lane's activation row

  // B fragment offsets (cfg = cg*2 + {0,1})
  const int b0off = (cg * 2)     * 8192 + lane * 8;
  const int b1off = (cg * 2 + 1) * 8192 + lane * 8;

  // ---------------- phase 0: params + features into T0 ---------------------
  if (t < 256){
    // FiLM param staging: Pgs = gamma, C2s[l] = b_l*gm + bt
    const float gm = gamma[bi * 256 + t];
    const float bt = beta[bi * 256 + t];
    Pgs[t] = gm;
    C2s[0][t] = fmaf(b0[t], gm, bt);
    C2s[1][t] = fmaf(b1[t], gm, bt);
    C2s[2][t] = fmaf(b2[t], gm, bt);
    C2s[3][t] = fmaf(b3[t], gm, bt);

    const int r = t >> 2, q = t & 3;
    const int n = n0 + r;
    const float cy = coords[2 * n], cx = coords[2 * n + 1];

    if (q == 0){
      if (peh){
        const unsigned short* ph = peh + (size_t)n * 48;
#pragma unroll
        for (int u = 0; u < 6; ++u){
          us8 vh = *reinterpret_cast<const us8*>(ph + u * 8);
          *reinterpret_cast<us8*>(&Ah0[ACOL(r, u * 8)]) = vh;
        }
      } else {
        float e[48];
        e[0] = cy; e[1] = cx;
#pragma unroll
        for (int i = 0; i < 10; ++i){
          float f = PI_F * (float)(1 << i);
          float sy, cyv, sx, cxv;
          sincosf(cy * f, &sy, &cyv);
          sincosf(cx * f, &sx, &cxv);
          e[2 + 4 * i] = sy;
          e[3 + 4 * i] = sx;
          e[4 + 4 * i] = cyv;
          e[5 + 4 * i] = cxv;
        }
#pragma unroll
        for (int j = 42; j < 48; ++j) e[j] = 0.0f;
#pragma unroll
        for (int u = 0; u < 6; ++u){
          us8 vh;
#pragma unroll
          for (int j = 0; j < 8; ++j) vh[j] = f2h(e[8 * u + j]);
          *reinterpret_cast<us8*>(&Ah0[ACOL(r, u * 8)]) = vh;
        }
      }
    }
    if (q == 1){   // zero pad cols 240..255
      us8 z = {0,0,0,0,0,0,0,0};
      *reinterpret_cast<us8*>(&Ah0[ACOL(r, 240)]) = z;
      *reinterpret_cast<us8*>(&Ah0[ACOL(r, 248)]) = z;
    }

    // bilinear sample 16 channels per thread from each pyramid level
#pragma unroll
    for (int L = 0; L < 3; ++L){
      const int HL = 64 >> L;
      const float* g = (L == 0) ? fg : ((L == 1) ? p1 : p2);
      float yy = (cy + 1.0f) * 0.5f * (HL - 1);
      float xx = (cx + 1.0f) * 0.5f * (HL - 1);
      float y0f = floorf(yy), x0f = floorf(xx);
      float wy = yy - y0f, wx = xx - x0f;
      int y0 = (int)y0f, x0 = (int)x0f;
      y0 = min(max(y0, 0), HL - 1); x0 = min(max(x0, 0), HL - 1);
      int y1 = min(y0 + 1, HL - 1), x1 = min(x0 + 1, HL - 1);
      const int c0 = q * 16;
      const float* g00 = g + (((bi * HL + y0) * HL) + x0) * 64 + c0;
      const float* g01 = g + (((bi * HL + y0) * HL) + x1) * 64 + c0;
      const float* g10 = g + (((bi * HL + y1) * HL) + x0) * 64 + c0;
      const float* g11 = g + (((bi * HL + y1) * HL) + x1) * 64 + c0;
      float w00 = (1 - wy) * (1 - wx), w01 = (1 - wy) * wx;
      float w10 = wy * (1 - wx),       w11 = wy * wx;
      float o[16];
#pragma unroll
      for (int u = 0; u < 4; ++u){
        float4 v0 = *reinterpret_cast<const float4*>(g00 + 4 * u);
        float4 v1 = *reinterpret_cast<const float4*>(g01 + 4 * u);
        float4 v2 = *reinterpret_cast<const float4*>(g10 + 4 * u);
        float4 v3 = *reinterpret_cast<const float4*>(g11 + 4 * u);
        o[4*u+0] = w00*v0.x + w01*v1.x + w10*v2.x + w11*v3.x;
        o[4*u+1] = w00*v0.y + w01*v1.y + w10*v2.y + w11*v3.y;
        o[4*u+2] = w00*v0.z + w01*v1.z + w10*v2.z + w11*v3.z;
        o[4*u+3] = w00*v0.w + w01*v1.w + w10*v2.w + w11*v3.w;
      }
      us8 h0, h1;
#pragma unroll
      for (int j = 0; j < 8; ++j){
        h0[j] = f2h(o[j]);
        h1[j] = f2h(o[8 + j]);
      }
      const int colb = 48 + 64 * L + 16 * q;
      *reinterpret_cast<us8*>(&Ah0[ACOL(r, colb)])     = h0;
      *reinterpret_cast<us8*>(&Ah0[ACOL(r, colb + 8)]) = h1;
    }
  }

  // B-prefetch ring: layer-0 fragments 0..7 issued BEFORE the barrier
  f16x8 bf0[8], bf1[8];
#pragma unroll
  for (int p = 0; p < 8; ++p){
    bf0[p] = LDW(WTh + b0off + p * 512);
    bf1[p] = LDW(WTh + b1off + p * 512);
  }
  __syncthreads();

  // ---------------- phase 1: 4 FiLM-gelu MLP layers (32x32x16, swapped) ----
  // Double-buffered tiles: layer l reads T[l&1], writes T[1^(l&1)]; ONE barrier.
#pragma unroll
  for (int l = 0; l < 4; ++l){
    const unsigned short* Rh   = (l & 1) ? Ah1 : Ah0;   // read tile
    unsigned short*       Wh_t = (l & 1) ? Ah0 : Ah1;   // write tile
    const unsigned short* Wcur = WTh + l * 65536;
    const unsigned short* Wnxt = WTh + (l + 1) * 65536; // only used when l<3

    f32x16 accA, accB;
#pragma unroll
    for (int j = 0; j < 16; ++j){ accA[j] = 0.0f; accB[j] = 0.0f; }

#pragma unroll
    for (int ks = 0; ks < 16; ++ks){
      const int cur = ks & 7;                 // compile-time (full unroll)
      const int kc = ks * 16 + lhi * 8;
      f16x8 ah  = LDW(&Rh[ACOL(arow, kc)]);
      f16x8 b0v = bf0[cur], b1v = bf1[cur];
      // ring refill: same-layer frag ks+8, or next layer's frag ks-8
      if (ks < 8){
        bf0[cur] = LDW(Wcur + b0off + (ks + 8) * 512);
        bf1[cur] = LDW(Wcur + b1off + (ks + 8) * 512);
      } else if (l < 3){
        bf0[cur] = LDW(Wnxt + b0off + (ks - 8) * 512);
        bf1[cur] = LDW(Wnxt + b1off + (ks - 8) * 512);
      }
      // SWAPPED operands: weights first (D reg = weight col),
      // activations second (D lane = activation row)
      accA = __builtin_amdgcn_mfma_f32_32x32x16_f16(b0v, ah, accA, 0, 0, 0);
      accB = __builtin_amdgcn_mfma_f32_32x32x16_f16(b1v, ah, accB, 0, 0, 0);
    }
    // no barrier here: epilogue writes the OTHER tile (disjoint).

    // epilogue: reg-quad g covers cols colb..colb+3 at row arow
#define EPI32(ACC, CF) do { \
      _Pragma("unroll") \
      for (int g = 0; g < 4; ++g){ \
        const int colb = cg * 64 + (CF) * 32 + 4 * lhi + 8 * g; \
        const float4 gm4 = *reinterpret_cast<const float4*>(&Pgs[colb]); \
        const float4 c24 = *reinterpret_cast<const float4*>(&C2s[l][colb]); \
        us4 hh; \
        { float v = fmaf((ACC)[4*g+0], gm4.x, c24.x); hh[0] = f2h(fast_gelu(v)); } \
        { float v = fmaf((ACC)[4*g+1], gm4.y, c24.y); hh[1] = f2h(fast_gelu(v)); } \
        { float v = fmaf((ACC)[4*g+2], gm4.z, c24.z); hh[2] = f2h(fast_gelu(v)); } \
        { float v = fmaf((ACC)[4*g+3], gm4.w, c24.w); hh[3] = f2h(fast_gelu(v)); } \
        *reinterpret_cast<us4*>(&Wh_t[ACOL(arow, colb)]) = hh; \
      } } while(0)
    EPI32(accA, 0);
    EPI32(accB, 1);
#undef EPI32
    __syncthreads();   // writes to T[next] visible before next layer reads it
  }

  // ---------------- phase 2: output head (256 -> 3) + tanh (16x16 path) ----
  // Final activations in T0 (l=3 wrote T0).
  if (wv < 4){
    f32x4 ao = (f32x4){0.0f, 0.0f, 0.0f, 0.0f};
#pragma unroll
    for (int ks = 0; ks < 8; ++ks){
      const int kc = ks * 32 + lg * 8;
      f16x8 va = LDW(&Ah0[ACOL(wv * 16 + l15, kc)]);
      f16x8 vb = LDW(&WoT[(ks * 64 + lane) * 8]);
      ao = __builtin_amdgcn_mfma_f32_16x16x32_f16(va, vb, ao, 0, 0, 0);
    }
    if (l15 < 3){
      const float bo = bout[l15];
#pragma unroll
      for (int rg2 = 0; rg2 < 4; ++rg2){
        const int row = wv * 16 + lg * 4 + rg2;
        out[((size_t)bi * 16384 + n0 + row) * 3 + l15] = fast_tanh(ao[rg2] + bo);
      }
    }
  }
}

// ------------------------------- launch --------------------------------------
extern "C" void kernel_launch(void* const* d_in, const int* in_sizes, int n_in,
                              void* d_out, int out_size, void* d_ws, size_t ws_size,
                              hipStream_t stream){
  (void)in_sizes; (void)n_in; (void)out_size;
  const float* fg     = (const float*)d_in[0];
  const float* cv     = (const float*)d_in[1];
  const float* coords = (const float*)d_in[2];
  const float* Wc     = (const float*)d_in[3];
  const float* bc     = (const float*)d_in[4];
  const float* W0     = (const float*)d_in[5];
  const float* b0     = (const float*)d_in[6];
  const float* W1     = (const float*)d_in[7];
  const float* b1     = (const float*)d_in[8];
  const float* W2     = (const float*)d_in[9];
  const float* b2     = (const float*)d_in[10];
  const float* W3     = (const float*)d_in[11];
  const float* b3     = (const float*)d_in[12];
  const float* Wout   = (const float*)d_in[13];
  const float* bout   = (const float*)d_in[14];

  char* ws = (char*)d_ws;
  float*          p1    = (float*)(ws);                    // 8*32*32*64 f32 = 2 MB
  float*          p2    = (float*)(ws + 2097152);          // 8*16*16*64 f32 = 512 KB
  unsigned short* WTh   = (unsigned short*)(ws + 2621440); // 4*256*256 f16 = 512 KB
  unsigned short* WoT   = (unsigned short*)(ws + 3670016); // 8*64*8 f16
  float*          gam   = (float*)(ws + 3678208);          // 8*256 f32
  float*          bet   = (float*)(ws + 3686400);          // 8*256 f32
  // PE table (optional, 1.5 MB)
  const size_t PEH_OFF = 4194304, PE_END = 5767168;
  bool use_pe = (ws_size >= PE_END);
  unsigned short* PEh = use_pe ? (unsigned short*)(ws + PEH_OFF) : nullptr;
  float* outp = (float*)d_out;

  pyr_kernel<<<dim3(2048), dim3(256), 0, stream>>>(fg, p1, 32, 32, 2.0f);
  pyr_kernel<<<dim3(512),  dim3(256), 0, stream>>>(fg, p2, 16, 16, 4.0f);
  prep_wt  <<<dim3(1024),  dim3(256), 0, stream>>>(W0, W1, W2, W3, WTh);
  prep_misc<<<dim3(32),    dim3(256), 0, stream>>>(cv, Wc, bc, Wout, gam, bet, WoT);
  if (use_pe)
    pe_kernel<<<dim3(768), dim3(256), 0, stream>>>(coords, PEh);
  dec_main <<<dim3(2048),  dim3(512), 0, stream>>>(fg, coords, p1, p2, WTh, WoT,
                                                   PEh,
                                                   gam, bet, b0, b1, b2, b3, bout, outp);
}